// Round 3
// baseline (1035.498 us; speedup 1.0000x reference)
//
#include <hip/hip_runtime.h>
#include <cstdint>

#define NROW 6144
#define HDIM 512
#define DOUT 256
#define NEG_INF (-__builtin_inff())

typedef _Float16 half8 __attribute__((ext_vector_type(8)));
typedef _Float16 half4v __attribute__((ext_vector_type(4)));
typedef float f32x4 __attribute__((ext_vector_type(4)));

__device__ __forceinline__ void gld_lds16(void* lds, const void* g) {
  __builtin_amdgcn_global_load_lds(
      (const __attribute__((address_space(1))) void*)g,
      (__attribute__((address_space(3))) void*)lds, 16, 0, 0);
}

// ================= gemm256: C = A[M,K] * B[N,K]^T, f16 in, f32 acc, f16 out =================
// 256x256 tile, BK=32, 512 threads = 8 waves (2M x 4N). Double-buffered LDS with
// counted-vmcnt pipeline across raw s_barriers (loads for tile t+1/t+2 in flight during
// compute of t). LDS XOR-swizzle: 16B slot p of row r holds logical slot p ^ ((r>>1)&3);
// staging pre-swizzles the GLOBAL source (global_load_lds writes linearly), reads apply
// the same XOR -> 8 consecutive lanes cover all 32 banks exactly once.
// Split-K: store f16 partial at C + blockIdx.z*MN (MN=0, gridDim.z=1 for direct).
__global__ __launch_bounds__(512)
void gemm256(const _Float16* __restrict__ A, int lda,
             const _Float16* __restrict__ B, int ldb,
             _Float16* __restrict__ C, int ldc, int Kc, long MN)
{
  __shared__ _Float16 As[2][256][32];
  __shared__ _Float16 Bs[2][256][32];
  const int tid = threadIdx.x;
  const int wave = tid >> 6, lane = tid & 63;
  const int wr = wave >> 2, wc = wave & 3;

  // XCD-aware bijective block swizzle over the flattened grid (nwg % 8 == 0 in all uses)
  const int gx = gridDim.x, gy = gridDim.y;
  const int nwg = gx * gy * gridDim.z;
  int lin = (blockIdx.z * gy + blockIdx.y) * gx + blockIdx.x;
  int swz = (nwg % 8 == 0) ? ((lin % 8) * (nwg >> 3) + (lin >> 3)) : lin;
  const int bx = swz % gx;
  const int by = (swz / gx) % gy;
  const int bz = swz / (gx * gy);
  const int row0 = bx * 256, col0 = by * 256;
  const int kbase = bz * Kc;
  const int nt = Kc >> 5;              // K-tiles of 32

  // staging: 1024 granules (16B) per matrix tile; thread stages g = li*512 + wave*64 + lane
  const int g0 = wave * 64 + lane;
  const int g1 = g0 + 512;
  const int r0g = g0 >> 2, p0g = g0 & 3;
  const int r1g = g1 >> 2, p1g = g1 & 3;
  const size_t aoff0 = (size_t)(row0 + r0g) * lda + (p0g ^ ((r0g >> 1) & 3)) * 8;
  const size_t aoff1 = (size_t)(row0 + r1g) * lda + (p1g ^ ((r1g >> 1) & 3)) * 8;
  const size_t boff0 = (size_t)(col0 + r0g) * ldb + (p0g ^ ((r0g >> 1) & 3)) * 8;
  const size_t boff1 = (size_t)(col0 + r1g) * ldb + (p1g ^ ((r1g >> 1) & 3)) * 8;
  const int ldsh0 = (wave * 64) * 8;          // wave-uniform LDS base (halves); HW adds lane*16B
  const int ldsh1 = (512 + wave * 64) * 8;

  f32x4 acc[8][4];
  const f32x4 vzero = {0.f, 0.f, 0.f, 0.f};
  #pragma unroll
  for (int f = 0; f < 8; ++f)
    #pragma unroll
    for (int j = 0; j < 4; ++j)
      acc[f][j] = vzero;

  const int fr = lane & 15, sq = lane >> 4;

  // prologue: stage tiles 0 and 1
  {
    const _Float16* a = A + kbase;
    const _Float16* b = B + kbase;
    gld_lds16(&As[0][0][0] + ldsh0, a + aoff0);
    gld_lds16(&As[0][0][0] + ldsh1, a + aoff1);
    gld_lds16(&Bs[0][0][0] + ldsh0, b + boff0);
    gld_lds16(&Bs[0][0][0] + ldsh1, b + boff1);
    gld_lds16(&As[1][0][0] + ldsh0, a + 32 + aoff0);
    gld_lds16(&As[1][0][0] + ldsh1, a + 32 + aoff1);
    gld_lds16(&Bs[1][0][0] + ldsh0, b + 32 + boff0);
    gld_lds16(&Bs[1][0][0] + ldsh1, b + 32 + boff1);
  }
  asm volatile("s_waitcnt vmcnt(4)" ::: "memory");
  __builtin_amdgcn_s_barrier();
  asm volatile("" ::: "memory");

  for (int t = 0; t < nt; ++t) {
    const int buf = t & 1;
    half8 bfr[4];
    #pragma unroll
    for (int j = 0; j < 4; ++j) {
      int r = wc * 64 + j * 16 + fr;
      bfr[j] = *(const half8*)&Bs[buf][r][(sq ^ ((r >> 1) & 3)) * 8];
    }
    #pragma unroll
    for (int mh = 0; mh < 2; ++mh) {
      half8 afr[4];
      #pragma unroll
      for (int i = 0; i < 4; ++i) {
        int r = wr * 128 + mh * 64 + i * 16 + fr;
        afr[i] = *(const half8*)&As[buf][r][(sq ^ ((r >> 1) & 3)) * 8];
      }
      __builtin_amdgcn_s_setprio(1);
      #pragma unroll
      for (int i = 0; i < 4; ++i)
        #pragma unroll
        for (int j = 0; j < 4; ++j)
          acc[mh * 4 + i][j] =
              __builtin_amdgcn_mfma_f32_16x16x32_f16(afr[i], bfr[j], acc[mh * 4 + i][j], 0, 0, 0);
      __builtin_amdgcn_s_setprio(0);
    }
    if (t + 1 < nt) {
      asm volatile("s_waitcnt lgkmcnt(0)" ::: "memory");  // my reads of buf done before others overwrite
      __builtin_amdgcn_s_barrier();
      if (t + 2 < nt) {
        const _Float16* a = A + kbase + (t + 2) * 32;
        const _Float16* b = B + kbase + (t + 2) * 32;
        gld_lds16(&As[buf][0][0] + ldsh0, a + aoff0);
        gld_lds16(&As[buf][0][0] + ldsh1, a + aoff1);
        gld_lds16(&Bs[buf][0][0] + ldsh0, b + boff0);
        gld_lds16(&Bs[buf][0][0] + ldsh1, b + boff1);
        asm volatile("s_waitcnt vmcnt(4)" ::: "memory");  // tile t+1 landed; t+2 still in flight
      } else {
        asm volatile("s_waitcnt vmcnt(0)" ::: "memory");  // tail: drain t+1
      }
      __builtin_amdgcn_s_barrier();
      asm volatile("" ::: "memory");
    }
  }

  _Float16* dst = C + (size_t)bz * MN;
  #pragma unroll
  for (int f = 0; f < 8; ++f)
    #pragma unroll
    for (int j = 0; j < 4; ++j)
      #pragma unroll
      for (int r = 0; r < 4; ++r) {
        int row = row0 + wr * 128 + f * 16 + sq * 4 + r;   // C/D: col=lane&15, row=(lane>>4)*4+reg
        int col = col0 + wc * 64 + j * 16 + fr;
        dst[(size_t)row * ldc + col] = (_Float16)acc[f][j][r];
      }
}

// ================= 128x128 GEMM (m97 structure) for the small-N GEMMs =================
__global__ __launch_bounds__(256)
void gemm_f16(const _Float16* __restrict__ A, int lda,
              const _Float16* __restrict__ B, int ldb,
              float* __restrict__ Cf, _Float16* __restrict__ Ch, int ldc,
              int Kc, _Float16* __restrict__ Pk, long MN)
{
  __shared__ _Float16 As[128][32];
  __shared__ _Float16 Bs[128][32];
  const int tid = threadIdx.x;
  const int wave = tid >> 6, lane = tid & 63;
  const int wr = wave >> 1, wc = wave & 1;
  const int row0 = blockIdx.x * 128, col0 = blockIdx.y * 128;
  const int kbase = blockIdx.z * Kc;

  const int sr = lane >> 2;
  const int sk = ((lane & 3) ^ ((lane >> 3) & 3)) * 8;

  f32x4 acc[4][4];
  const f32x4 vzero = {0.f, 0.f, 0.f, 0.f};
  #pragma unroll
  for (int i = 0; i < 4; ++i)
    #pragma unroll
    for (int j = 0; j < 4; ++j)
      acc[i][j] = vzero;

  const int fr = lane & 15;
  const int fk = (((lane >> 4) ^ ((fr >> 1) & 3))) * 8;

  for (int k0 = kbase; k0 < kbase + Kc; k0 += 32) {
    #pragma unroll
    for (int c = 0; c < 2; ++c) {
      int rbase = c * 64 + wave * 16;
      gld_lds16(&As[rbase][0], A + (size_t)(row0 + rbase + sr) * lda + k0 + sk);
      gld_lds16(&Bs[rbase][0], B + (size_t)(col0 + rbase + sr) * ldb + k0 + sk);
    }
    __syncthreads();
    half8 af[4], bf[4];
    #pragma unroll
    for (int i = 0; i < 4; ++i)
      af[i] = *(const half8*)&As[wr * 64 + i * 16 + fr][fk];
    #pragma unroll
    for (int j = 0; j < 4; ++j)
      bf[j] = *(const half8*)&Bs[wc * 64 + j * 16 + fr][fk];
    #pragma unroll
    for (int i = 0; i < 4; ++i)
      #pragma unroll
      for (int j = 0; j < 4; ++j)
        acc[i][j] = __builtin_amdgcn_mfma_f32_16x16x32_f16(af[i], bf[j], acc[i][j], 0, 0, 0);
    __syncthreads();
  }

  const int lr = (lane >> 4) * 4;
  const int lc = lane & 15;
  if (Pk) {
    _Float16* dst = Pk + (size_t)blockIdx.z * MN;
    #pragma unroll
    for (int i = 0; i < 4; ++i)
      #pragma unroll
      for (int j = 0; j < 4; ++j)
        #pragma unroll
        for (int r = 0; r < 4; ++r) {
          int row = row0 + wr * 64 + i * 16 + lr + r;
          int col = col0 + wc * 64 + j * 16 + lc;
          dst[(size_t)row * ldc + col] = (_Float16)acc[i][j][r];
        }
    return;
  }
  #pragma unroll
  for (int i = 0; i < 4; ++i)
    #pragma unroll
    for (int j = 0; j < 4; ++j)
      #pragma unroll
      for (int r = 0; r < 4; ++r) {
        int row = row0 + wr * 64 + i * 16 + lr + r;
        int col = col0 + wc * 64 + j * 16 + lc;
        float v = acc[i][j][r];
        if (Cf) Cf[(size_t)row * ldc + col] = v;
        if (Ch) Ch[(size_t)row * ldc + col] = (_Float16)v;
      }
}

// ---------------- split-K reduce: Y = rowscale(row) * sum_z Pk[z]; writes f32/f16
__global__ __launch_bounds__(256)
void reduce_splitk(const _Float16* __restrict__ Pk, long MN, int S, int cshift,
                   const float* __restrict__ rowscale,
                   float* __restrict__ Yf, _Float16* __restrict__ Yh)
{
  long n4 = MN >> 2;
  for (long i = (long)blockIdx.x * 256 + threadIdx.x; i < n4; i += (long)gridDim.x * 256) {
    float s0 = 0, s1 = 0, s2 = 0, s3 = 0;
    for (int z = 0; z < S; ++z) {
      half4v p = ((const half4v*)(Pk + (size_t)z * MN))[i];
      s0 += (float)p[0]; s1 += (float)p[1]; s2 += (float)p[2]; s3 += (float)p[3];
    }
    if (rowscale) {
      float sc = rowscale[(i * 4) >> cshift];
      s0 *= sc; s1 *= sc; s2 *= sc; s3 *= sc;
    }
    if (Yf) {
      float4 o; o.x = s0; o.y = s1; o.z = s2; o.w = s3;
      ((float4*)Yf)[i] = o;
    }
    if (Yh) {
      half4v o;
      o[0] = (_Float16)s0; o[1] = (_Float16)s1; o[2] = (_Float16)s2; o[3] = (_Float16)s3;
      ((half4v*)Yh)[i] = o;
    }
  }
}

// ---------------- fused: degree row-sum -> dis, and f32 -> f16 adjacency convert
__global__ __launch_bounds__(256)
void degree_convert(const float* __restrict__ A, _Float16* __restrict__ Ah,
                    float* __restrict__ dis)
{
  const int row = blockIdx.x;
  const float* a = A + (size_t)row * NROW;
  _Float16* o = Ah + (size_t)row * NROW;
  float s = 0.f;
  #pragma unroll
  for (int it = 0; it < 6; ++it) {
    int j = it * 1024 + threadIdx.x * 4;
    float4 v = *(const float4*)&a[j];
    s += v.x + v.y + v.z + v.w;
    half4v h;
    h[0] = (_Float16)v.x; h[1] = (_Float16)v.y; h[2] = (_Float16)v.z; h[3] = (_Float16)v.w;
    *(half4v*)&o[j] = h;
  }
  #pragma unroll
  for (int off = 32; off; off >>= 1) s += __shfl_xor(s, off);
  __shared__ float red[4];
  if ((threadIdx.x & 63) == 0) red[threadIdx.x >> 6] = s;
  __syncthreads();
  if (threadIdx.x == 0) {
    float d = red[0] + red[1] + red[2] + red[3];
    dis[row] = (d > 0.f) ? rsqrtf(fmaxf(d, 1e-12f)) : 0.f;
  }
}

// ---------------- adj (f32 0/1) -> bitmask [NROW][192] u32
__global__ __launch_bounds__(192)
void build_mask(const float* __restrict__ adj, uint32_t* __restrict__ bits)
{
  const int row = blockIdx.x;
  const int w = threadIdx.x;
  const float* a = adj + (size_t)row * NROW + w * 32;
  uint32_t m = 0;
  #pragma unroll
  for (int q = 0; q < 8; ++q) {
    float4 x = *(const float4*)&a[q * 4];
    m |= (x.x != 0.f ? 1u : 0u) << (q * 4 + 0);
    m |= (x.y != 0.f ? 1u : 0u) << (q * 4 + 1);
    m |= (x.z != 0.f ? 1u : 0u) << (q * 4 + 2);
    m |= (x.w != 0.f ? 1u : 0u) << (q * 4 + 3);
  }
  bits[(size_t)row * 192 + w] = m;
}

// ---------------- f32 -> f16 convert with scale
__global__ __launch_bounds__(256)
void convert_f16(const float* __restrict__ x, _Float16* __restrict__ y, float scale, long n4)
{
  for (long i = (long)blockIdx.x * 256 + threadIdx.x; i < n4; i += (long)gridDim.x * 256) {
    float4 v = ((const float4*)x)[i];
    half4v o;
    o[0] = (_Float16)(v.x * scale);
    o[1] = (_Float16)(v.y * scale);
    o[2] = (_Float16)(v.z * scale);
    o[3] = (_Float16)(v.w * scale);
    ((half4v*)y)[i] = o;
  }
}

// ---------------- dst[c][r] = f16(src[r][c] * rowscale[r]); src f32 [R,C], dst [C,R]
__global__ __launch_bounds__(256)
void transpose_scale_f16(const float* __restrict__ src, const float* __restrict__ rowscale,
                         _Float16* __restrict__ dst, int R, int C)
{
  __shared__ _Float16 tile[64][72];
  const int c0 = blockIdx.x * 64, r0 = blockIdx.y * 64;
  const int tx4 = (threadIdx.x & 15) * 4, ty = threadIdx.x >> 4;
  #pragma unroll
  for (int p = 0; p < 4; ++p) {
    int r = p * 16 + ty;
    float4 v = *(const float4*)&src[(size_t)(r0 + r) * C + c0 + tx4];
    float sc = rowscale ? rowscale[r0 + r] : 1.0f;
    tile[tx4 + 0][r] = (_Float16)(v.x * sc);
    tile[tx4 + 1][r] = (_Float16)(v.y * sc);
    tile[tx4 + 2][r] = (_Float16)(v.z * sc);
    tile[tx4 + 3][r] = (_Float16)(v.w * sc);
  }
  __syncthreads();
  #pragma unroll
  for (int p = 0; p < 4; ++p) {
    int c = p * 16 + ty;
    half4v o;
    o[0] = tile[c][tx4 + 0];
    o[1] = tile[c][tx4 + 1];
    o[2] = tile[c][tx4 + 2];
    o[3] = tile[c][tx4 + 3];
    *(half4v*)&dst[(size_t)(c0 + c) * R + r0 + tx4] = o;
  }
}

// ---------------- dst[c][r] = src[r*ld + c]; f16 -> f16 transpose
__global__ __launch_bounds__(256)
void transpose_f16(const _Float16* __restrict__ src, int ld,
                   _Float16* __restrict__ dst, int R, int C)
{
  __shared__ _Float16 tile[64][72];
  const int c0 = blockIdx.x * 64, r0 = blockIdx.y * 64;
  const int tx4 = (threadIdx.x & 15) * 4, ty = threadIdx.x >> 4;
  #pragma unroll
  for (int p = 0; p < 4; ++p) {
    int r = p * 16 + ty;
    half4v v = *(const half4v*)&src[(size_t)(r0 + r) * ld + c0 + tx4];
    tile[tx4 + 0][r] = v[0];
    tile[tx4 + 1][r] = v[1];
    tile[tx4 + 2][r] = v[2];
    tile[tx4 + 3][r] = v[3];
  }
  __syncthreads();
  #pragma unroll
  for (int p = 0; p < 4; ++p) {
    int c = p * 16 + ty;
    half4v o;
    o[0] = tile[c][tx4 + 0];
    o[1] = tile[c][tx4 + 1];
    o[2] = tile[c][tx4 + 2];
    o[3] = tile[c][tx4 + 3];
    *(half4v*)&dst[(size_t)(c0 + c) * R + r0 + tx4] = o;
  }
}

// ---------------- in-place masked softmax over f16 scores; writes UNNORMALIZED exp
// and linv[row] = 1/sum (normalization folded into PV reduce rowscale)
__global__ __launch_bounds__(256)
void softmax_mask16(_Float16* __restrict__ Sf, const uint32_t* __restrict__ bits,
                    float* __restrict__ linv)
{
  const int row = blockIdx.x;
  _Float16* s = Sf + (size_t)row * NROW;
  const uint32_t* b = bits + (size_t)row * 192;
  const int tid = threadIdx.x;
  float v[24];
  float m = NEG_INF;
  #pragma unroll
  for (int it = 0; it < 3; ++it) {
    int j = it * 2048 + tid * 8;
    half8 sv = *(const half8*)&s[j];
    uint32_t w = (b[j >> 5] >> (j & 31)) & 0xffu;
    #pragma unroll
    for (int e = 0; e < 8; ++e) {
      float x = ((w >> e) & 1u) ? (float)sv[e] : NEG_INF;
      v[it * 8 + e] = x;
      m = fmaxf(m, x);
    }
  }
  #pragma unroll
  for (int off = 32; off; off >>= 1) m = fmaxf(m, __shfl_xor(m, off));
  __shared__ float red[4];
  const int lane = tid & 63, wave = tid >> 6;
  if (lane == 0) red[wave] = m;
  __syncthreads();
  m = fmaxf(fmaxf(red[0], red[1]), fmaxf(red[2], red[3]));
  __syncthreads();
  float l = 0.f;
  #pragma unroll
  for (int k = 0; k < 24; ++k) {
    float e = (v[k] == NEG_INF) ? 0.f : __expf(v[k] - m);
    v[k] = e; l += e;
  }
  #pragma unroll
  for (int off = 32; off; off >>= 1) l += __shfl_xor(l, off);
  if (lane == 0) red[wave] = l;
  __syncthreads();
  l = red[0] + red[1] + red[2] + red[3];
  if (tid == 0) linv[row] = (l > 0.f) ? (1.f / l) : 0.f;
  #pragma unroll
  for (int it = 0; it < 3; ++it) {
    int j = it * 2048 + tid * 8;
    half8 o;
    #pragma unroll
    for (int e = 0; e < 8; ++e) o[e] = (_Float16)v[it * 8 + e];
    *(half8*)&s[j] = o;
  }
}

// ---------------- BN partial sums over 128-row slices (f16 input)
__global__ __launch_bounds__(256)
void bn_partial(const _Float16* __restrict__ X, int C,
                float* __restrict__ psum, float* __restrict__ psq)
{
  const int b = blockIdx.x;
  const int tid = threadIdx.x;
  const _Float16* x = X + (size_t)b * 128 * C;
  float s0 = 0, q0 = 0, s1 = 0, q1 = 0;
  for (int r = 0; r < 128; ++r) {
    float a = (float)x[(size_t)r * C + tid];
    s0 += a; q0 += a * a;
    if (C == 512) {
      float c2 = (float)x[(size_t)r * C + tid + 256];
      s1 += c2; q1 += c2 * c2;
    }
  }
  psum[b * C + tid] = s0; psq[b * C + tid] = q0;
  if (C == 512) { psum[b * C + tid + 256] = s1; psq[b * C + tid + 256] = q1; }
}

__global__ void bn_finalize(const float* __restrict__ psum, const float* __restrict__ psq,
                            int C, const float* __restrict__ g, const float* __restrict__ beta,
                            float* __restrict__ scale, float* __restrict__ shift)
{
  int c = threadIdx.x + blockIdx.x * blockDim.x;
  if (c >= C) return;
  float s = 0, q = 0;
  for (int b = 0; b < 48; ++b) { s += psum[b * C + c]; q += psq[b * C + c]; }
  const float invN = 1.0f / 6144.0f;
  float mean = s * invN;
  float var = q * invN - mean * mean;
  float rstd = rsqrtf(fmaxf(var, 0.f) + 1e-5f);
  float sc = g[c] * rstd;
  scale[c] = sc;
  shift[c] = beta[c] - mean * sc;
}

// ---------------- y = relu?(x*scale[c]+shift[c]) + residual(f16); f16 input
__global__ __launch_bounds__(256)
void bn_apply(const _Float16* __restrict__ X, const float* __restrict__ scale,
              const float* __restrict__ shift, const _Float16* __restrict__ residual,
              float* __restrict__ Yf, _Float16* __restrict__ Yh,
              int Cmask, long total, int do_relu)
{
  for (long i = (long)blockIdx.x * 256 + threadIdx.x; i < total; i += (long)gridDim.x * 256) {
    int c = (int)(i & Cmask);
    float v = (float)X[i] * scale[c] + shift[c];
    if (do_relu) v = fmaxf(v, 0.f);
    if (residual) v += (float)residual[i];
    if (Yf) Yf[i] = v;
    if (Yh) Yh[i] = (_Float16)v;
  }
}

extern "C" void kernel_launch(void* const* d_in, const int* in_sizes, int n_in,
                              void* d_out, int out_size, void* d_ws, size_t ws_size,
                              hipStream_t stream)
{
  (void)in_sizes; (void)n_in; (void)out_size; (void)ws_size;
  const float* X     = (const float*)d_in[0];
  const float* adj   = (const float*)d_in[1];
  const float* adjg  = (const float*)d_in[2];
  const float* Wp    = (const float*)d_in[3];
  const float* gp    = (const float*)d_in[5];
  const float* betap = (const float*)d_in[6];

  float* out_h     = (float*)d_out;                       // [6144,256]
  float* out_embed = out_h + (size_t)NROW * DOUT;         // [6144,512]

  char* base = (char*)d_ws;
  size_t off = 0;
  auto alloc = [&](size_t bytes) -> void* {
    void* p = base + off;
    off += (bytes + 255) & ~(size_t)255;
    return p;
  };

  const long MN512 = (long)NROW * 512;

  _Float16* Ag  = (_Float16*)alloc((size_t)NROW * NROW * 2);   // adjg f16; reused as scores Sf
  _Float16* Sf  = Ag;
  uint32_t* bits = (uint32_t*)alloc((size_t)NROW * 192 * 4);
  _Float16* Pk  = (_Float16*)alloc((size_t)8 * MN512 * 2);     // split-K partials (f16)
  _Float16* XsT = (_Float16*)alloc((size_t)HDIM * NROW * 2);
  _Float16* Yh16 = (_Float16*)alloc((size_t)NROW * HDIM * 2);
  _Float16* Wph = (_Float16*)alloc((size_t)HDIM * HDIM * 2);
  _Float16* QKVW[3];
  for (int i = 0; i < 3; ++i) QKVW[i] = (_Float16*)alloc((size_t)1536 * HDIM * 2);
  _Float16* Woh[3];
  Woh[0] = (_Float16*)alloc((size_t)512 * 512 * 2);
  Woh[1] = (_Float16*)alloc((size_t)512 * 512 * 2);
  Woh[2] = (_Float16*)alloc((size_t)256 * 512 * 2);
  _Float16* QKVh = (_Float16*)alloc((size_t)NROW * 1536 * 2);
  _Float16* VTh  = (_Float16*)alloc((size_t)HDIM * NROW * 2);
  _Float16* AVh  = (_Float16*)alloc((size_t)NROW * HDIM * 2);
  _Float16* xh   = (_Float16*)alloc((size_t)NROW * HDIM * 2);  // pre-BN buffer (f16)
  _Float16* hb16A = (_Float16*)alloc((size_t)NROW * HDIM * 2);
  _Float16* hb16B = (_Float16*)alloc((size_t)NROW * HDIM * 2);
  float* dis  = (float*)alloc((size_t)NROW * 4);
  float* linv = (float*)alloc((size_t)NROW * 4);
  float* psum = (float*)alloc((size_t)48 * 512 * 4);
  float* psq  = (float*)alloc((size_t)48 * 512 * 4);
  float* bnsc = (float*)alloc(512 * 4);
  float* bnsh = (float*)alloc(512 * 4);

  const float qk_scale = 0.21022410381342863f;  // 512^(-1/4); folded into both Wq and Wk

  degree_convert<<<NROW, 256, 0, stream>>>(adjg, Ag, dis);
  build_mask<<<NROW, 192, 0, stream>>>(adj, bits);
  transpose_scale_f16<<<dim3(8, 96), 256, 0, stream>>>(X, dis, XsT, NROW, HDIM);
  convert_f16<<<128, 256, 0, stream>>>(Wp, Wph, 1.f, 512 * 512 / 4);
  for (int i = 0; i < 3; ++i) {
    const float* Wq = (const float*)d_in[7 + i * 7 + 0];
    const float* Wk = (const float*)d_in[7 + i * 7 + 1];
    const float* Wv = (const float*)d_in[7 + i * 7 + 2];
    const float* Wo = (const float*)d_in[7 + i * 7 + 3];
    int o = (i < 2) ? 512 : 256;
    convert_f16<<<128, 256, 0, stream>>>(Wq, QKVW[i], qk_scale, 512 * 512 / 4);
    convert_f16<<<128, 256, 0, stream>>>(Wk, QKVW[i] + 512 * 512, qk_scale, 512 * 512 / 4);
    convert_f16<<<128, 256, 0, stream>>>(Wv, QKVW[i] + 2 * 512 * 512, 1.f, 512 * 512 / 4);
    convert_f16<<<128, 256, 0, stream>>>(Wo, Woh[i], 1.f, (long)o * 512 / 4);
  }

  // ---- embedding: h = BN( rowscale(dis) * (Ag @ XsT^T) @ Wp^T )   (bias cancels in BN)
  gemm256<<<dim3(24, 2, 8), 512, 0, stream>>>(Ag, NROW, XsT, NROW, Pk, 512, 768, MN512);
  reduce_splitk<<<1536, 256, 0, stream>>>(Pk, MN512, 8, 9, dis, nullptr, Yh16);
  gemm_f16<<<dim3(48, 4), 256, 0, stream>>>(Yh16, HDIM, Wph, HDIM, nullptr, xh, HDIM,
                                            512, nullptr, 0);
  bn_partial<<<48, 256, 0, stream>>>(xh, 512, psum, psq);
  bn_finalize<<<2, 256, 0, stream>>>(psum, psq, 512, gp, betap, bnsc, bnsh);
  bn_apply<<<2048, 256, 0, stream>>>(xh, bnsc, bnsh, nullptr, out_embed, hb16A,
                                     511, MN512, 0);

  _Float16* hbuf[2] = {hb16A, hb16B};
  int cur = 0;
  for (int i = 0; i < 3; ++i) {
    int o = (i < 2) ? 512 : 256;
    const float* gl = (const float*)d_in[7 + i * 7 + 5];
    const float* bl = (const float*)d_in[7 + i * 7 + 6];
    _Float16* hin = hbuf[cur];

    // fused QKV projection: [6144,1536]
    gemm_f16<<<dim3(48, 12), 256, 0, stream>>>(hin, HDIM, QKVW[i], HDIM, nullptr, QKVh, 1536,
                                               512, nullptr, 0);
    transpose_f16<<<dim3(8, 96), 256, 0, stream>>>(QKVh + 1024, 1536, VTh, NROW, HDIM);
    // scores (full, f16) then in-place masked softmax (unnormalized exp + linv)
    gemm256<<<dim3(24, 24), 512, 0, stream>>>(QKVh, 1536, QKVh + 512, 1536, Sf, NROW, 512, 0);
    softmax_mask16<<<NROW, 256, 0, stream>>>(Sf, bits, linv);
    // attn @ V (split-K 8), normalization via rowscale=linv in reduce
    gemm256<<<dim3(24, 2, 8), 512, 0, stream>>>(Sf, NROW, VTh, NROW, Pk, 512, 768, MN512);
    reduce_splitk<<<1536, 256, 0, stream>>>(Pk, MN512, 8, 9, linv, nullptr, AVh);
    // @ Wo^T (split-K 4; bias cancels in BN)
    long MNo = (long)NROW * o;
    gemm_f16<<<dim3(48, o / 128, 4), 256, 0, stream>>>(AVh, HDIM, Woh[i], HDIM,
                                                       nullptr, nullptr, o, 128, Pk, MNo);
    reduce_splitk<<<1536, 256, 0, stream>>>(Pk, MNo, 4, (o == 512) ? 9 : 8, nullptr,
                                            nullptr, xh);
    bn_partial<<<48, 256, 0, stream>>>(xh, o, psum, psq);
    bn_finalize<<<2, 256, 0, stream>>>(psum, psq, o, gl, bl, bnsc, bnsh);
    if (i < 2) {
      bn_apply<<<2048, 256, 0, stream>>>(xh, bnsc, bnsh, hin, nullptr, hbuf[cur ^ 1],
                                         o - 1, (long)NROW * o, 1);
      cur ^= 1;
    } else {
      bn_apply<<<2048, 256, 0, stream>>>(xh, bnsc, bnsh, nullptr, out_h, nullptr,
                                         o - 1, (long)NROW * o, 1);
    }
  }
}

// Round 5
// 997.811 us; speedup vs baseline: 1.0378x; 1.0378x over previous
//
#include <hip/hip_runtime.h>
#include <cstdint>

#define NROW 6144
#define HDIM 512
#define DOUT 256
#define NEG_INF (-__builtin_inff())

typedef _Float16 half8 __attribute__((ext_vector_type(8)));
typedef _Float16 half4v __attribute__((ext_vector_type(4)));
typedef float f32x4 __attribute__((ext_vector_type(4)));

#define BARRIER() asm volatile("s_barrier" ::: "memory")
#define LGKM0()   asm volatile("s_waitcnt lgkmcnt(0)" ::: "memory")
#define VMCNT4()  asm volatile("s_waitcnt vmcnt(4)" ::: "memory")
#define VMCNT0()  asm volatile("s_waitcnt vmcnt(0)" ::: "memory")

__device__ __forceinline__ void gld_lds16(void* lds, const void* g) {
  __builtin_amdgcn_global_load_lds(
      (const __attribute__((address_space(1))) void*)g,
      (__attribute__((address_space(3))) void*)lds, 16, 0, 0);
}

// ============== gemm256: 8-phase 256x256 GEMM (race-fixed stage ledger) ==============
// C[M,N] = A[M,K] * B[N,K]^T (row-major, f16 in, f32 acc, f16 out).
// 8 waves (2Mx4N), BK=64, 128KB dbuf LDS. Read regions per tile: ph1 dsA(b,0)
// [rows 0-63,128-191]+dsBlo(b)[0-31,64-95,128-159,192-223]; ph2 dsBhi(b); ph3
// dsA(b,1)[64-127,192-255]; ph4 none => A-halves (128-row) dead only after ph3
// (buf0)/ph7 (buf1); B-halves dead after ph2/ph6. Stage ledger (stage >= 1
// closing barrier after region's last read):
//   ph1 A(1,h0,T+1)  ph2 A(1,h1,T+1)  ph3 B(0,h0,T+2)  ph4 B(0,h1,T+2)
//   ph5 A(0,h0,T+2)  ph6 A(0,h1,T+2)  ph7 B(1,h0,T+3)  ph8 B(1,h1,T+3)
// vmcnt(4)+barrier at ph4 (guarantees tile T+1 complete: 12 outstanding,
// oldest 8 = T+1's loads) and ph8 (guarantees tile T+2). Tail: vmcnt(0).
// LDS swizzle: 16B slot s of row r holds logical s^(r&7); global source
// pre-swizzled (global_load_lds writes linearly), reads apply the same XOR.
__global__ __launch_bounds__(512, 2)
void gemm256(const _Float16* __restrict__ A, int lda,
             const _Float16* __restrict__ B, int ldb,
             _Float16* __restrict__ C, int ldc, int Kc, long MN)
{
  __shared__ _Float16 As[2][256][64];
  __shared__ _Float16 Bs[2][256][64];
  const int tid = threadIdx.x;
  const int wave = tid >> 6, lane = tid & 63;
  const int wr = wave >> 2, wc = wave & 3;            // 2 x 4 wave grid

  // XCD-aware bijective block swizzle (all grids used have nwg % 8 == 0)
  const int gx = gridDim.x, gy = gridDim.y;
  const int nwg = gx * gy * gridDim.z;
  int lin = (blockIdx.z * gy + blockIdx.y) * gx + blockIdx.x;
  int swz = (nwg % 8 == 0) ? ((lin % 8) * (nwg >> 3) + (lin >> 3)) : lin;
  const int bx = swz % gx, by = (swz / gx) % gy, bz = swz / (gx * gy);
  const int row0 = bx * 256, col0 = by * 256;
  const _Float16* Ab = A + (size_t)row0 * lda + (size_t)bz * Kc;
  const _Float16* Bb = B + (size_t)col0 * ldb + (size_t)bz * Kc;
  const int nt = Kc >> 6;                             // K-tiles of 64 (even)

  // staging: wave w covers rows {h*128 + w*8 .. +7} and {h*128+64+w*8 ..}
  const int srow = lane >> 3;                         // row within 8-row slice
  const int sgr  = (lane & 7) ^ srow;                 // pre-swizzled src 16B granule

  auto stageA = [&](int buf, int h, int t) {
    const _Float16* src = Ab + (size_t)(h * 128 + wave * 8 + srow) * lda + t * 64 + sgr * 8;
    gld_lds16(&As[buf][h * 128 + wave * 8][0], src);
    gld_lds16(&As[buf][h * 128 + 64 + wave * 8][0], src + (size_t)64 * lda);
  };
  auto stageB = [&](int buf, int h, int t) {
    const _Float16* src = Bb + (size_t)(h * 128 + wave * 8 + srow) * ldb + t * 64 + sgr * 8;
    gld_lds16(&Bs[buf][h * 128 + wave * 8][0], src);
    gld_lds16(&Bs[buf][h * 128 + 64 + wave * 8][0], src + (size_t)64 * ldb);
  };

  // fragment reads (swizzled): physical slot = (ks*4+sq) ^ (row&7)
  const int fr = lane & 15, sq = lane >> 4, fx = fr & 7;
  half8 af[4][2], bLo[2][2], bHi[2][2];
  f32x4 acc[8][4];
  const f32x4 vzero = {0.f, 0.f, 0.f, 0.f};
  #pragma unroll
  for (int f = 0; f < 8; ++f)
    #pragma unroll
    for (int j = 0; j < 4; ++j)
      acc[f][j] = vzero;

  auto dsA = [&](int buf, int mh) {
    #pragma unroll
    for (int i = 0; i < 4; ++i)
      #pragma unroll
      for (int ks = 0; ks < 2; ++ks)
        af[i][ks] = *(const half8*)&As[buf][wr * 128 + mh * 64 + i * 16 + fr]
                                          [((ks * 4 + sq) ^ fx) * 8];
  };
  auto dsBlo = [&](int buf) {
    #pragma unroll
    for (int jj = 0; jj < 2; ++jj)
      #pragma unroll
      for (int ks = 0; ks < 2; ++ks)
        bLo[jj][ks] = *(const half8*)&Bs[buf][wc * 64 + jj * 16 + fr]
                                            [((ks * 4 + sq) ^ fx) * 8];
  };
  auto dsBhi = [&](int buf) {
    #pragma unroll
    for (int jj = 0; jj < 2; ++jj)
      #pragma unroll
      for (int ks = 0; ks < 2; ++ks)
        bHi[jj][ks] = *(const half8*)&Bs[buf][wc * 64 + 32 + jj * 16 + fr]
                                            [((ks * 4 + sq) ^ fx) * 8];
  };
  auto mQlo = [&](int fb) {   // quadrant vs B-lo -> acc cols 0..1
    __builtin_amdgcn_s_setprio(1);
    #pragma unroll
    for (int i = 0; i < 4; ++i)
      #pragma unroll
      for (int jj = 0; jj < 2; ++jj)
        #pragma unroll
        for (int ks = 0; ks < 2; ++ks)
          acc[fb + i][jj] = __builtin_amdgcn_mfma_f32_16x16x32_f16(
              af[i][ks], bLo[jj][ks], acc[fb + i][jj], 0, 0, 0);
    __builtin_amdgcn_s_setprio(0);
  };
  auto mQhi = [&](int fb) {   // quadrant vs B-hi -> acc cols 2..3
    __builtin_amdgcn_s_setprio(1);
    #pragma unroll
    for (int i = 0; i < 4; ++i)
      #pragma unroll
      for (int jj = 0; jj < 2; ++jj)
        #pragma unroll
        for (int ks = 0; ks < 2; ++ks)
          acc[fb + i][2 + jj] = __builtin_amdgcn_mfma_f32_16x16x32_f16(
              af[i][ks], bHi[jj][ks], acc[fb + i][2 + jj], 0, 0, 0);
    __builtin_amdgcn_s_setprio(0);
  };

  // prologue: tile0 fully into buf0, tile1's B into buf1 (A(1,*) staged ph1/ph2).
  // 12 loads; vmcnt(4) waits the oldest 8 = all of tile0; leaves tile1-B in flight.
  stageA(0, 0, 0); stageA(0, 1, 0); stageB(0, 0, 0); stageB(0, 1, 0);
  stageB(1, 0, 1); stageB(1, 1, 1);
  VMCNT4();
  BARRIER();

  for (int T = 0; T < nt; T += 2) {
    const bool pipe = (T + 2 < nt);
    // ---- tile T (buf0) ----
    // ph1: quad(0,lo)
    dsA(0, 0); dsBlo(0);
    stageA(1, 0, T + 1);                       // As[1] h0: last read prev ph7
    BARRIER(); LGKM0(); mQlo(0); BARRIER();
    // ph2: quad(0,hi)
    dsBhi(0);
    stageA(1, 1, T + 1);                       // As[1] h1: last read prev ph7
    BARRIER(); LGKM0(); mQhi(0); BARRIER();
    // ph3: quad(1,hi)
    dsA(0, 1);
    if (pipe) stageB(0, 0, T + 2);             // Bs[0] h0: last read ph2
    BARRIER(); LGKM0(); mQhi(4); BARRIER();
    // ph4: quad(1,lo); tile T+1 must be landed after this barrier
    if (pipe) { stageB(0, 1, T + 2); VMCNT4(); } else { VMCNT0(); }
    BARRIER(); mQlo(4); BARRIER();
    // ---- tile T+1 (buf1) ----
    // ph5
    dsA(1, 0); dsBlo(1);
    if (pipe) stageA(0, 0, T + 2);             // As[0] h0: last read ph3
    BARRIER(); LGKM0(); mQlo(0); BARRIER();
    // ph6
    dsBhi(1);
    if (pipe) stageA(0, 1, T + 2);             // As[0] h1: last read ph3
    BARRIER(); LGKM0(); mQhi(0); BARRIER();
    // ph7
    dsA(1, 1);
    if (pipe) stageB(1, 0, T + 3);             // Bs[1] h0: last read ph6
    BARRIER(); LGKM0(); mQhi(4); BARRIER();
    // ph8: tile T+2 must be landed after this barrier
    if (pipe) { stageB(1, 1, T + 3); VMCNT4(); } else { VMCNT0(); }
    BARRIER(); mQlo(4); BARRIER();
  }

  // epilogue: C/D layout col=lane&15, row=(lane>>4)*4+reg (m89)
  _Float16* dst = C + (size_t)bz * MN;
  #pragma unroll
  for (int f = 0; f < 8; ++f)
    #pragma unroll
    for (int j = 0; j < 4; ++j)
      #pragma unroll
      for (int r = 0; r < 4; ++r) {
        int row = row0 + wr * 128 + f * 16 + sq * 4 + r;
        int col = col0 + wc * 64 + j * 16 + fr;
        dst[(size_t)row * ldc + col] = (_Float16)acc[f][j][r];
      }
}

// ================= 128x128 GEMM (m97 structure) for the small-N GEMMs =================
__global__ __launch_bounds__(256)
void gemm_f16(const _Float16* __restrict__ A, int lda,
              const _Float16* __restrict__ B, int ldb,
              float* __restrict__ Cf, _Float16* __restrict__ Ch, int ldc,
              int Kc, _Float16* __restrict__ Pk, long MN)
{
  __shared__ _Float16 As[128][32];
  __shared__ _Float16 Bs[128][32];
  const int tid = threadIdx.x;
  const int wave = tid >> 6, lane = tid & 63;
  const int wr = wave >> 1, wc = wave & 1;
  const int row0 = blockIdx.x * 128, col0 = blockIdx.y * 128;
  const int kbase = blockIdx.z * Kc;

  const int sr = lane >> 2;
  const int sk = ((lane & 3) ^ ((lane >> 3) & 3)) * 8;

  f32x4 acc[4][4];
  const f32x4 vzero = {0.f, 0.f, 0.f, 0.f};
  #pragma unroll
  for (int i = 0; i < 4; ++i)
    #pragma unroll
    for (int j = 0; j < 4; ++j)
      acc[i][j] = vzero;

  const int fr = lane & 15;
  const int fk = (((lane >> 4) ^ ((fr >> 1) & 3))) * 8;

  for (int k0 = kbase; k0 < kbase + Kc; k0 += 32) {
    #pragma unroll
    for (int c = 0; c < 2; ++c) {
      int rbase = c * 64 + wave * 16;
      gld_lds16(&As[rbase][0], A + (size_t)(row0 + rbase + sr) * lda + k0 + sk);
      gld_lds16(&Bs[rbase][0], B + (size_t)(col0 + rbase + sr) * ldb + k0 + sk);
    }
    __syncthreads();
    half8 af[4], bf[4];
    #pragma unroll
    for (int i = 0; i < 4; ++i)
      af[i] = *(const half8*)&As[wr * 64 + i * 16 + fr][fk];
    #pragma unroll
    for (int j = 0; j < 4; ++j)
      bf[j] = *(const half8*)&Bs[wc * 64 + j * 16 + fr][fk];
    #pragma unroll
    for (int i = 0; i < 4; ++i)
      #pragma unroll
      for (int j = 0; j < 4; ++j)
        acc[i][j] = __builtin_amdgcn_mfma_f32_16x16x32_f16(af[i], bf[j], acc[i][j], 0, 0, 0);
    __syncthreads();
  }

  const int lr = (lane >> 4) * 4;
  const int lc = lane & 15;
  if (Pk) {
    _Float16* dst = Pk + (size_t)blockIdx.z * MN;
    #pragma unroll
    for (int i = 0; i < 4; ++i)
      #pragma unroll
      for (int j = 0; j < 4; ++j)
        #pragma unroll
        for (int r = 0; r < 4; ++r) {
          int row = row0 + wr * 64 + i * 16 + lr + r;
          int col = col0 + wc * 64 + j * 16 + lc;
          dst[(size_t)row * ldc + col] = (_Float16)acc[i][j][r];
        }
    return;
  }
  #pragma unroll
  for (int i = 0; i < 4; ++i)
    #pragma unroll
    for (int j = 0; j < 4; ++j)
      #pragma unroll
      for (int r = 0; r < 4; ++r) {
        int row = row0 + wr * 64 + i * 16 + lr + r;
        int col = col0 + wc * 64 + j * 16 + lc;
        float v = acc[i][j][r];
        if (Cf) Cf[(size_t)row * ldc + col] = v;
        if (Ch) Ch[(size_t)row * ldc + col] = (_Float16)v;
      }
}

// ---------------- split-K reduce: Y = rowscale(row) * sum_z Pk[z]; writes f32/f16
__global__ __launch_bounds__(256)
void reduce_splitk(const _Float16* __restrict__ Pk, long MN, int S, int cshift,
                   const float* __restrict__ rowscale,
                   float* __restrict__ Yf, _Float16* __restrict__ Yh)
{
  long n4 = MN >> 2;
  for (long i = (long)blockIdx.x * 256 + threadIdx.x; i < n4; i += (long)gridDim.x * 256) {
    float s0 = 0, s1 = 0, s2 = 0, s3 = 0;
    for (int z = 0; z < S; ++z) {
      half4v p = ((const half4v*)(Pk + (size_t)z * MN))[i];
      s0 += (float)p[0]; s1 += (float)p[1]; s2 += (float)p[2]; s3 += (float)p[3];
    }
    if (rowscale) {
      float sc = rowscale[(i * 4) >> cshift];
      s0 *= sc; s1 *= sc; s2 *= sc; s3 *= sc;
    }
    if (Yf) {
      float4 o; o.x = s0; o.y = s1; o.z = s2; o.w = s3;
      ((float4*)Yf)[i] = o;
    }
    if (Yh) {
      half4v o;
      o[0] = (_Float16)s0; o[1] = (_Float16)s1; o[2] = (_Float16)s2; o[3] = (_Float16)s3;
      ((half4v*)Yh)[i] = o;
    }
  }
}

// ---------------- fused: degree row-sum -> dis, and f32 -> f16 adjacency convert
__global__ __launch_bounds__(256)
void degree_convert(const float* __restrict__ A, _Float16* __restrict__ Ah,
                    float* __restrict__ dis)
{
  const int row = blockIdx.x;
  const float* a = A + (size_t)row * NROW;
  _Float16* o = Ah + (size_t)row * NROW;
  float s = 0.f;
  #pragma unroll
  for (int it = 0; it < 6; ++it) {
    int j = it * 1024 + threadIdx.x * 4;
    float4 v = *(const float4*)&a[j];
    s += v.x + v.y + v.z + v.w;
    half4v h;
    h[0] = (_Float16)v.x; h[1] = (_Float16)v.y; h[2] = (_Float16)v.z; h[3] = (_Float16)v.w;
    *(half4v*)&o[j] = h;
  }
  #pragma unroll
  for (int off = 32; off; off >>= 1) s += __shfl_xor(s, off);
  __shared__ float red[4];
  if ((threadIdx.x & 63) == 0) red[threadIdx.x >> 6] = s;
  __syncthreads();
  if (threadIdx.x == 0) {
    float d = red[0] + red[1] + red[2] + red[3];
    dis[row] = (d > 0.f) ? rsqrtf(fmaxf(d, 1e-12f)) : 0.f;
  }
}

// ---------------- adj (f32 0/1) -> bitmask [NROW][192] u32
__global__ __launch_bounds__(192)
void build_mask(const float* __restrict__ adj, uint32_t* __restrict__ bits)
{
  const int row = blockIdx.x;
  const int w = threadIdx.x;
  const float* a = adj + (size_t)row * NROW + w * 32;
  uint32_t m = 0;
  #pragma unroll
  for (int q = 0; q < 8; ++q) {
    float4 x = *(const float4*)&a[q * 4];
    m |= (x.x != 0.f ? 1u : 0u) << (q * 4 + 0);
    m |= (x.y != 0.f ? 1u : 0u) << (q * 4 + 1);
    m |= (x.z != 0.f ? 1u : 0u) << (q * 4 + 2);
    m |= (x.w != 0.f ? 1u : 0u) << (q * 4 + 3);
  }
  bits[(size_t)row * 192 + w] = m;
}

// ---------------- f32 -> f16 convert with scale
__global__ __launch_bounds__(256)
void convert_f16(const float* __restrict__ x, _Float16* __restrict__ y, float scale, long n4)
{
  for (long i = (long)blockIdx.x * 256 + threadIdx.x; i < n4; i += (long)gridDim.x * 256) {
    float4 v = ((const float4*)x)[i];
    half4v o;
    o[0] = (_Float16)(v.x * scale);
    o[1] = (_Float16)(v.y * scale);
    o[2] = (_Float16)(v.z * scale);
    o[3] = (_Float16)(v.w * scale);
    ((half4v*)y)[i] = o;
  }
}

// ---------------- dst[c][r] = f16(src[r][c] * rowscale[r]); src f32 [R,C], dst [C,R]
__global__ __launch_bounds__(256)
void transpose_scale_f16(const float* __restrict__ src, const float* __restrict__ rowscale,
                         _Float16* __restrict__ dst, int R, int C)
{
  __shared__ _Float16 tile[64][72];
  const int c0 = blockIdx.x * 64, r0 = blockIdx.y * 64;
  const int tx4 = (threadIdx.x & 15) * 4, ty = threadIdx.x >> 4;
  #pragma unroll
  for (int p = 0; p < 4; ++p) {
    int r = p * 16 + ty;
    float4 v = *(const float4*)&src[(size_t)(r0 + r) * C + c0 + tx4];
    float sc = rowscale ? rowscale[r0 + r] : 1.0f;
    tile[tx4 + 0][r] = (_Float16)(v.x * sc);
    tile[tx4 + 1][r] = (_Float16)(v.y * sc);
    tile[tx4 + 2][r] = (_Float16)(v.z * sc);
    tile[tx4 + 3][r] = (_Float16)(v.w * sc);
  }
  __syncthreads();
  #pragma unroll
  for (int p = 0; p < 4; ++p) {
    int c = p * 16 + ty;
    half4v o;
    o[0] = tile[c][tx4 + 0];
    o[1] = tile[c][tx4 + 1];
    o[2] = tile[c][tx4 + 2];
    o[3] = tile[c][tx4 + 3];
    *(half4v*)&dst[(size_t)(c0 + c) * R + r0 + tx4] = o;
  }
}

// ---------------- dst[c][r] = src[r*ld + c]; f16 -> f16 transpose
__global__ __launch_bounds__(256)
void transpose_f16(const _Float16* __restrict__ src, int ld,
                   _Float16* __restrict__ dst, int R, int C)
{
  __shared__ _Float16 tile[64][72];
  const int c0 = blockIdx.x * 64, r0 = blockIdx.y * 64;
  const int tx4 = (threadIdx.x & 15) * 4, ty = threadIdx.x >> 4;
  #pragma unroll
  for (int p = 0; p < 4; ++p) {
    int r = p * 16 + ty;
    half4v v = *(const half4v*)&src[(size_t)(r0 + r) * ld + c0 + tx4];
    tile[tx4 + 0][r] = v[0];
    tile[tx4 + 1][r] = v[1];
    tile[tx4 + 2][r] = v[2];
    tile[tx4 + 3][r] = v[3];
  }
  __syncthreads();
  #pragma unroll
  for (int p = 0; p < 4; ++p) {
    int c = p * 16 + ty;
    half4v o;
    o[0] = tile[c][tx4 + 0];
    o[1] = tile[c][tx4 + 1];
    o[2] = tile[c][tx4 + 2];
    o[3] = tile[c][tx4 + 3];
    *(half4v*)&dst[(size_t)(c0 + c) * R + r0 + tx4] = o;
  }
}

// ---------------- in-place masked softmax over f16 scores; writes UNNORMALIZED exp
// and linv[row] = 1/sum (normalization folded into PV reduce rowscale)
__global__ __launch_bounds__(256)
void softmax_mask16(_Float16* __restrict__ Sf, const uint32_t* __restrict__ bits,
                    float* __restrict__ linv)
{
  const int row = blockIdx.x;
  _Float16* s = Sf + (size_t)row * NROW;
  const uint32_t* b = bits + (size_t)row * 192;
  const int tid = threadIdx.x;
  float v[24];
  float m = NEG_INF;
  #pragma unroll
  for (int it = 0; it < 3; ++it) {
    int j = it * 2048 + tid * 8;
    half8 sv = *(const half8*)&s[j];
    uint32_t w = (b[j >> 5] >> (j & 31)) & 0xffu;
    #pragma unroll
    for (int e = 0; e < 8; ++e) {
      float x = ((w >> e) & 1u) ? (float)sv[e] : NEG_INF;
      v[it * 8 + e] = x;
      m = fmaxf(m, x);
    }
  }
  #pragma unroll
  for (int off = 32; off; off >>= 1) m = fmaxf(m, __shfl_xor(m, off));
  __shared__ float red[4];
  const int lane = tid & 63, wave = tid >> 6;
  if (lane == 0) red[wave] = m;
  __syncthreads();
  m = fmaxf(fmaxf(red[0], red[1]), fmaxf(red[2], red[3]));
  __syncthreads();
  float l = 0.f;
  #pragma unroll
  for (int k = 0; k < 24; ++k) {
    float e = (v[k] == NEG_INF) ? 0.f : __expf(v[k] - m);
    v[k] = e; l += e;
  }
  #pragma unroll
  for (int off = 32; off; off >>= 1) l += __shfl_xor(l, off);
  if (lane == 0) red[wave] = l;
  __syncthreads();
  l = red[0] + red[1] + red[2] + red[3];
  if (tid == 0) linv[row] = (l > 0.f) ? (1.f / l) : 0.f;
  #pragma unroll
  for (int it = 0; it < 3; ++it) {
    int j = it * 2048 + tid * 8;
    half8 o;
    #pragma unroll
    for (int e = 0; e < 8; ++e) o[e] = (_Float16)v[it * 8 + e];
    *(half8*)&s[j] = o;
  }
}

// ---------------- BN partial sums over 128-row slices (f16 input)
__global__ __launch_bounds__(256)
void bn_partial(const _Float16* __restrict__ X, int C,
                float* __restrict__ psum, float* __restrict__ psq)
{
  const int b = blockIdx.x;
  const int tid = threadIdx.x;
  const _Float16* x = X + (size_t)b * 128 * C;
  float s0 = 0, q0 = 0, s1 = 0, q1 = 0;
  for (int r = 0; r < 128; ++r) {
    float a = (float)x[(size_t)r * C + tid];
    s0 += a; q0 += a * a;
    if (C == 512) {
      float c2 = (float)x[(size_t)r * C + tid + 256];
      s1 += c2; q1 += c2 * c2;
    }
  }
  psum[b * C + tid] = s0; psq[b * C + tid] = q0;
  if (C == 512) { psum[b * C + tid + 256] = s1; psq[b * C + tid + 256] = q1; }
}

__global__ void bn_finalize(const float* __restrict__ psum, const float* __restrict__ psq,
                            int C, const float* __restrict__ g, const float* __restrict__ beta,
                            float* __restrict__ scale, float* __restrict__ shift)
{
  int c = threadIdx.x + blockIdx.x * blockDim.x;
  if (c >= C) return;
  float s = 0, q = 0;
  for (int b = 0; b < 48; ++b) { s += psum[b * C + c]; q += psq[b * C + c]; }
  const float invN = 1.0f / 6144.0f;
  float mean = s * invN;
  float var = q * invN - mean * mean;
  float rstd = rsqrtf(fmaxf(var, 0.f) + 1e-5f);
  float sc = g[c] * rstd;
  scale[c] = sc;
  shift[c] = beta[c] - mean * sc;
}

// ---------------- y = relu?(x*scale[c]+shift[c]) + residual(f16); f16 input
__global__ __launch_bounds__(256)
void bn_apply(const _Float16* __restrict__ X, const float* __restrict__ scale,
              const float* __restrict__ shift, const _Float16* __restrict__ residual,
              float* __restrict__ Yf, _Float16* __restrict__ Yh,
              int Cmask, long total, int do_relu)
{
  for (long i = (long)blockIdx.x * 256 + threadIdx.x; i < total; i += (long)gridDim.x * 256) {
    int c = (int)(i & Cmask);
    float v = (float)X[i] * scale[c] + shift[c];
    if (do_relu) v = fmaxf(v, 0.f);
    if (residual) v += (float)residual[i];
    if (Yf) Yf[i] = v;
    if (Yh) Yh[i] = (_Float16)v;
  }
}

extern "C" void kernel_launch(void* const* d_in, const int* in_sizes, int n_in,
                              void* d_out, int out_size, void* d_ws, size_t ws_size,
                              hipStream_t stream)
{
  (void)in_sizes; (void)n_in; (void)out_size; (void)ws_size;
  const float* X     = (const float*)d_in[0];
  const float* adj   = (const float*)d_in[1];
  const float* adjg  = (const float*)d_in[2];
  const float* Wp    = (const float*)d_in[3];
  const float* gp    = (const float*)d_in[5];
  const float* betap = (const float*)d_in[6];

  float* out_h     = (float*)d_out;                       // [6144,256]
  float* out_embed = out_h + (size_t)NROW * DOUT;         // [6144,512]

  char* base = (char*)d_ws;
  size_t off = 0;
  auto alloc = [&](size_t bytes) -> void* {
    void* p = base + off;
    off += (bytes + 255) & ~(size_t)255;
    return p;
  };

  const long MN512 = (long)NROW * 512;

  _Float16* Ag  = (_Float16*)alloc((size_t)NROW * NROW * 2);   // adjg f16; reused as scores Sf
  _Float16* Sf  = Ag;
  uint32_t* bits = (uint32_t*)alloc((size_t)NROW * 192 * 4);
  _Float16* Pk  = (_Float16*)alloc((size_t)16 * MN512 * 2);    // split-K partials (f16)
  _Float16* XsT = (_Float16*)alloc((size_t)HDIM * NROW * 2);
  _Float16* Yh16 = (_Float16*)alloc((size_t)NROW * HDIM * 2);
  _Float16* Wph = (_Float16*)alloc((size_t)HDIM * HDIM * 2);
  _Float16* QKVW[3];
  for (int i = 0; i < 3; ++i) QKVW[i] = (_Float16*)alloc((size_t)1536 * HDIM * 2);
  _Float16* Woh[3];
  Woh[0] = (_Float16*)alloc((size_t)512 * 512 * 2);
  Woh[1] = (_Float16*)alloc((size_t)512 * 512 * 2);
  Woh[2] = (_Float16*)alloc((size_t)256 * 512 * 2);
  _Float16* QKVh = (_Float16*)alloc((size_t)NROW * 1536 * 2);
  _Float16* VTh  = (_Float16*)alloc((size_t)HDIM * NROW * 2);
  _Float16* AVh  = (_Float16*)alloc((size_t)NROW * HDIM * 2);
  _Float16* xh   = (_Float16*)alloc((size_t)NROW * HDIM * 2);  // pre-BN buffer (f16)
  _Float16* hb16A = (_Float16*)alloc((size_t)NROW * HDIM * 2);
  _Float16* hb16B = (_Float16*)alloc((size_t)NROW * HDIM * 2);
  float* dis  = (float*)alloc((size_t)NROW * 4);
  float* linv = (float*)alloc((size_t)NROW * 4);
  float* psum = (float*)alloc((size_t)48 * 512 * 4);
  float* psq  = (float*)alloc((size_t)48 * 512 * 4);
  float* bnsc = (float*)alloc(512 * 4);
  float* bnsh = (float*)alloc(512 * 4);

  const float qk_scale = 0.21022410381342863f;  // 512^(-1/4); folded into both Wq and Wk

  degree_convert<<<NROW, 256, 0, stream>>>(adjg, Ag, dis);
  build_mask<<<NROW, 192, 0, stream>>>(adj, bits);
  transpose_scale_f16<<<dim3(8, 96), 256, 0, stream>>>(X, dis, XsT, NROW, HDIM);
  convert_f16<<<128, 256, 0, stream>>>(Wp, Wph, 1.f, 512 * 512 / 4);
  for (int i = 0; i < 3; ++i) {
    const float* Wq = (const float*)d_in[7 + i * 7 + 0];
    const float* Wk = (const float*)d_in[7 + i * 7 + 1];
    const float* Wv = (const float*)d_in[7 + i * 7 + 2];
    const float* Wo = (const float*)d_in[7 + i * 7 + 3];
    int o = (i < 2) ? 512 : 256;
    convert_f16<<<128, 256, 0, stream>>>(Wq, QKVW[i], qk_scale, 512 * 512 / 4);
    convert_f16<<<128, 256, 0, stream>>>(Wk, QKVW[i] + 512 * 512, qk_scale, 512 * 512 / 4);
    convert_f16<<<128, 256, 0, stream>>>(Wv, QKVW[i] + 2 * 512 * 512, 1.f, 512 * 512 / 4);
    convert_f16<<<128, 256, 0, stream>>>(Wo, Woh[i], 1.f, (long)o * 512 / 4);
  }

  // ---- embedding: h = BN( rowscale(dis) * (Ag @ XsT^T) @ Wp^T )   (bias cancels in BN)
  gemm256<<<dim3(24, 2, 16), 512, 0, stream>>>(Ag, NROW, XsT, NROW, Pk, 512, 384, MN512);
  reduce_splitk<<<1536, 256, 0, stream>>>(Pk, MN512, 16, 9, dis, nullptr, Yh16);
  gemm_f16<<<dim3(48, 4), 256, 0, stream>>>(Yh16, HDIM, Wph, HDIM, nullptr, xh, HDIM,
                                            512, nullptr, 0);
  bn_partial<<<48, 256, 0, stream>>>(xh, 512, psum, psq);
  bn_finalize<<<2, 256, 0, stream>>>(psum, psq, 512, gp, betap, bnsc, bnsh);
  bn_apply<<<2048, 256, 0, stream>>>(xh, bnsc, bnsh, nullptr, out_embed, hb16A,
                                     511, MN512, 0);

  _Float16* hbuf[2] = {hb16A, hb16B};
  int cur = 0;
  for (int i = 0; i < 3; ++i) {
    int o = (i < 2) ? 512 : 256;
    const float* gl = (const float*)d_in[7 + i * 7 + 5];
    const float* bl = (const float*)d_in[7 + i * 7 + 6];
    _Float16* hin = hbuf[cur];

    // fused QKV projection: [6144,1536]
    gemm_f16<<<dim3(48, 12), 256, 0, stream>>>(hin, HDIM, QKVW[i], HDIM, nullptr, QKVh, 1536,
                                               512, nullptr, 0);
    transpose_f16<<<dim3(8, 96), 256, 0, stream>>>(QKVh + 1024, 1536, VTh, NROW, HDIM);
    // scores (full, f16) then in-place masked softmax (unnormalized exp + linv)
    gemm256<<<dim3(24, 24), 512, 0, stream>>>(QKVh, 1536, QKVh + 512, 1536, Sf, NROW, 512, 0);
    softmax_mask16<<<NROW, 256, 0, stream>>>(Sf, bits, linv);
    // attn @ V (split-K 16), normalization via rowscale=linv in reduce
    gemm256<<<dim3(24, 2, 16), 512, 0, stream>>>(Sf, NROW, VTh, NROW, Pk, 512, 384, MN512);
    reduce_splitk<<<1536, 256, 0, stream>>>(Pk, MN512, 16, 9, linv, nullptr, AVh);
    // @ Wo^T (split-K 4; bias cancels in BN)
    long MNo = (long)NROW * o;
    gemm_f16<<<dim3(48, o / 128, 4), 256, 0, stream>>>(AVh, HDIM, Woh[i], HDIM,
                                                       nullptr, nullptr, o, 128, Pk, MNo);
    reduce_splitk<<<1536, 256, 0, stream>>>(Pk, MNo, 4, (o == 512) ? 9 : 8, nullptr,
                                            nullptr, xh);
    bn_partial<<<48, 256, 0, stream>>>(xh, o, psum, psq);
    bn_finalize<<<2, 256, 0, stream>>>(psum, psq, o, gl, bl, bnsc, bnsh);
    if (i < 2) {
      bn_apply<<<2048, 256, 0, stream>>>(xh, bnsc, bnsh, hin, nullptr, hbuf[cur ^ 1],
                                         o - 1, (long)NROW * o, 1);
      cur ^= 1;
    } else {
      bn_apply<<<2048, 256, 0, stream>>>(xh, bnsc, bnsh, nullptr, out_h, nullptr,
                                         o - 1, (long)NROW * o, 1);
    }
  }
}

// Round 6
// 901.203 us; speedup vs baseline: 1.1490x; 1.1072x over previous
//
#include <hip/hip_runtime.h>
#include <cstdint>

#define NROW 6144
#define HDIM 512
#define DOUT 256
#define NEG_INF (-__builtin_inff())

typedef _Float16 half8 __attribute__((ext_vector_type(8)));
typedef _Float16 half4v __attribute__((ext_vector_type(4)));
typedef float f32x4 __attribute__((ext_vector_type(4)));

#define BARRIER() asm volatile("s_barrier" ::: "memory")
#define LGKM0()   asm volatile("s_waitcnt lgkmcnt(0)" ::: "memory")
#define VMCNT4()  asm volatile("s_waitcnt vmcnt(4)" ::: "memory")
#define VMCNT0()  asm volatile("s_waitcnt vmcnt(0)" ::: "memory")

__device__ __forceinline__ void gld_lds16(void* lds, const void* g) {
  __builtin_amdgcn_global_load_lds(
      (const __attribute__((address_space(1))) void*)g,
      (__attribute__((address_space(3))) void*)lds, 16, 0, 0);
}

// ============== gemm256: 8-phase 256x256 GEMM (proven round-5 schedule) ==============
// C[M,N] = A[M,K] * B[N,K]^T (row-major, f16 in, f32 acc, f16 out). See round-5
// stage ledger: ph1 A(1,h0,T+1) ph2 A(1,h1,T+1) ph3 B(0,h0,T+2) ph4 B(0,h1,T+2)
// ph5 A(0,h0,T+2) ph6 A(0,h1,T+2) ph7 B(1,h0,T+3) ph8 B(1,h1,T+3); vmcnt(4) at
// ph4/ph8; tail vmcnt(0). LDS swizzle: 16B slot s of row r holds logical s^(r&7).
__global__ __launch_bounds__(512, 2)
void gemm256(const _Float16* __restrict__ A, int lda,
             const _Float16* __restrict__ B, int ldb,
             _Float16* __restrict__ C, int ldc, int Kc, long MN)
{
  __shared__ _Float16 As[2][256][64];
  __shared__ _Float16 Bs[2][256][64];
  const int tid = threadIdx.x;
  const int wave = tid >> 6, lane = tid & 63;
  const int wr = wave >> 2, wc = wave & 3;            // 2 x 4 wave grid

  const int gx = gridDim.x, gy = gridDim.y;
  const int nwg = gx * gy * gridDim.z;
  int lin = (blockIdx.z * gy + blockIdx.y) * gx + blockIdx.x;
  int swz = (nwg % 8 == 0) ? ((lin % 8) * (nwg >> 3) + (lin >> 3)) : lin;
  const int bx = swz % gx, by = (swz / gx) % gy, bz = swz / (gx * gy);
  const int row0 = bx * 256, col0 = by * 256;
  const _Float16* Ab = A + (size_t)row0 * lda + (size_t)bz * Kc;
  const _Float16* Bb = B + (size_t)col0 * ldb + (size_t)bz * Kc;
  const int nt = Kc >> 6;                             // K-tiles of 64 (even)

  const int srow = lane >> 3;
  const int sgr  = (lane & 7) ^ srow;                 // pre-swizzled src 16B granule

  auto stageA = [&](int buf, int h, int t) {
    const _Float16* src = Ab + (size_t)(h * 128 + wave * 8 + srow) * lda + t * 64 + sgr * 8;
    gld_lds16(&As[buf][h * 128 + wave * 8][0], src);
    gld_lds16(&As[buf][h * 128 + 64 + wave * 8][0], src + (size_t)64 * lda);
  };
  auto stageB = [&](int buf, int h, int t) {
    const _Float16* src = Bb + (size_t)(h * 128 + wave * 8 + srow) * ldb + t * 64 + sgr * 8;
    gld_lds16(&Bs[buf][h * 128 + wave * 8][0], src);
    gld_lds16(&Bs[buf][h * 128 + 64 + wave * 8][0], src + (size_t)64 * ldb);
  };

  const int fr = lane & 15, sq = lane >> 4, fx = fr & 7;
  half8 af[4][2], bLo[2][2], bHi[2][2];
  f32x4 acc[8][4];
  const f32x4 vzero = {0.f, 0.f, 0.f, 0.f};
  #pragma unroll
  for (int f = 0; f < 8; ++f)
    #pragma unroll
    for (int j = 0; j < 4; ++j)
      acc[f][j] = vzero;

  auto dsA = [&](int buf, int mh) {
    #pragma unroll
    for (int i = 0; i < 4; ++i)
      #pragma unroll
      for (int ks = 0; ks < 2; ++ks)
        af[i][ks] = *(const half8*)&As[buf][wr * 128 + mh * 64 + i * 16 + fr]
                                          [((ks * 4 + sq) ^ fx) * 8];
  };
  auto dsBlo = [&](int buf) {
    #pragma unroll
    for (int jj = 0; jj < 2; ++jj)
      #pragma unroll
      for (int ks = 0; ks < 2; ++ks)
        bLo[jj][ks] = *(const half8*)&Bs[buf][wc * 64 + jj * 16 + fr]
                                            [((ks * 4 + sq) ^ fx) * 8];
  };
  auto dsBhi = [&](int buf) {
    #pragma unroll
    for (int jj = 0; jj < 2; ++jj)
      #pragma unroll
      for (int ks = 0; ks < 2; ++ks)
        bHi[jj][ks] = *(const half8*)&Bs[buf][wc * 64 + 32 + jj * 16 + fr]
                                            [((ks * 4 + sq) ^ fx) * 8];
  };
  auto mQlo = [&](int fb) {
    __builtin_amdgcn_s_setprio(1);
    #pragma unroll
    for (int i = 0; i < 4; ++i)
      #pragma unroll
      for (int jj = 0; jj < 2; ++jj)
        #pragma unroll
        for (int ks = 0; ks < 2; ++ks)
          acc[fb + i][jj] = __builtin_amdgcn_mfma_f32_16x16x32_f16(
              af[i][ks], bLo[jj][ks], acc[fb + i][jj], 0, 0, 0);
    __builtin_amdgcn_s_setprio(0);
  };
  auto mQhi = [&](int fb) {
    __builtin_amdgcn_s_setprio(1);
    #pragma unroll
    for (int i = 0; i < 4; ++i)
      #pragma unroll
      for (int jj = 0; jj < 2; ++jj)
        #pragma unroll
        for (int ks = 0; ks < 2; ++ks)
          acc[fb + i][2 + jj] = __builtin_amdgcn_mfma_f32_16x16x32_f16(
              af[i][ks], bHi[jj][ks], acc[fb + i][2 + jj], 0, 0, 0);
    __builtin_amdgcn_s_setprio(0);
  };

  stageA(0, 0, 0); stageA(0, 1, 0); stageB(0, 0, 0); stageB(0, 1, 0);
  stageB(1, 0, 1); stageB(1, 1, 1);
  VMCNT4();
  BARRIER();

  for (int T = 0; T < nt; T += 2) {
    const bool pipe = (T + 2 < nt);
    dsA(0, 0); dsBlo(0);
    stageA(1, 0, T + 1);
    BARRIER(); LGKM0(); mQlo(0); BARRIER();
    dsBhi(0);
    stageA(1, 1, T + 1);
    BARRIER(); LGKM0(); mQhi(0); BARRIER();
    dsA(0, 1);
    if (pipe) stageB(0, 0, T + 2);
    BARRIER(); LGKM0(); mQhi(4); BARRIER();
    if (pipe) { stageB(0, 1, T + 2); VMCNT4(); } else { VMCNT0(); }
    BARRIER(); mQlo(4); BARRIER();
    dsA(1, 0); dsBlo(1);
    if (pipe) stageA(0, 0, T + 2);
    BARRIER(); LGKM0(); mQlo(0); BARRIER();
    dsBhi(1);
    if (pipe) stageA(0, 1, T + 2);
    BARRIER(); LGKM0(); mQhi(0); BARRIER();
    dsA(1, 1);
    if (pipe) stageB(1, 0, T + 3);
    BARRIER(); LGKM0(); mQhi(4); BARRIER();
    if (pipe) { stageB(1, 1, T + 3); VMCNT4(); } else { VMCNT0(); }
    BARRIER(); mQlo(4); BARRIER();
  }

  _Float16* dst = C + (size_t)bz * MN;
  #pragma unroll
  for (int f = 0; f < 8; ++f)
    #pragma unroll
    for (int j = 0; j < 4; ++j)
      #pragma unroll
      for (int r = 0; r < 4; ++r) {
        int row = row0 + wr * 128 + f * 16 + sq * 4 + r;
        int col = col0 + wc * 64 + j * 16 + fr;
        dst[(size_t)row * ldc + col] = (_Float16)acc[f][j][r];
      }
}

// ================= 128x128 GEMM (m97 structure) for the small-N GEMMs =================
__global__ __launch_bounds__(256)
void gemm_f16(const _Float16* __restrict__ A, int lda,
              const _Float16* __restrict__ B, int ldb,
              float* __restrict__ Cf, _Float16* __restrict__ Ch, int ldc,
              int Kc, _Float16* __restrict__ Pk, long MN)
{
  __shared__ _Float16 As[128][32];
  __shared__ _Float16 Bs[128][32];
  const int tid = threadIdx.x;
  const int wave = tid >> 6, lane = tid & 63;
  const int wr = wave >> 1, wc = wave & 1;
  const int row0 = blockIdx.x * 128, col0 = blockIdx.y * 128;
  const int kbase = blockIdx.z * Kc;

  const int sr = lane >> 2;
  const int sk = ((lane & 3) ^ ((lane >> 3) & 3)) * 8;

  f32x4 acc[4][4];
  const f32x4 vzero = {0.f, 0.f, 0.f, 0.f};
  #pragma unroll
  for (int i = 0; i < 4; ++i)
    #pragma unroll
    for (int j = 0; j < 4; ++j)
      acc[i][j] = vzero;

  const int fr = lane & 15;
  const int fk = (((lane >> 4) ^ ((fr >> 1) & 3))) * 8;

  for (int k0 = kbase; k0 < kbase + Kc; k0 += 32) {
    #pragma unroll
    for (int c = 0; c < 2; ++c) {
      int rbase = c * 64 + wave * 16;
      gld_lds16(&As[rbase][0], A + (size_t)(row0 + rbase + sr) * lda + k0 + sk);
      gld_lds16(&Bs[rbase][0], B + (size_t)(col0 + rbase + sr) * ldb + k0 + sk);
    }
    __syncthreads();
    half8 af[4], bf[4];
    #pragma unroll
    for (int i = 0; i < 4; ++i)
      af[i] = *(const half8*)&As[wr * 64 + i * 16 + fr][fk];
    #pragma unroll
    for (int j = 0; j < 4; ++j)
      bf[j] = *(const half8*)&Bs[wc * 64 + j * 16 + fr][fk];
    #pragma unroll
    for (int i = 0; i < 4; ++i)
      #pragma unroll
      for (int j = 0; j < 4; ++j)
        acc[i][j] = __builtin_amdgcn_mfma_f32_16x16x32_f16(af[i], bf[j], acc[i][j], 0, 0, 0);
    __syncthreads();
  }

  const int lr = (lane >> 4) * 4;
  const int lc = lane & 15;
  if (Pk) {
    _Float16* dst = Pk + (size_t)blockIdx.z * MN;
    #pragma unroll
    for (int i = 0; i < 4; ++i)
      #pragma unroll
      for (int j = 0; j < 4; ++j)
        #pragma unroll
        for (int r = 0; r < 4; ++r) {
          int row = row0 + wr * 64 + i * 16 + lr + r;
          int col = col0 + wc * 64 + j * 16 + lc;
          dst[(size_t)row * ldc + col] = (_Float16)acc[i][j][r];
        }
    return;
  }
  #pragma unroll
  for (int i = 0; i < 4; ++i)
    #pragma unroll
    for (int j = 0; j < 4; ++j)
      #pragma unroll
      for (int r = 0; r < 4; ++r) {
        int row = row0 + wr * 64 + i * 16 + lr + r;
        int col = col0 + wc * 64 + j * 16 + lc;
        float v = acc[i][j][r];
        if (Cf) Cf[(size_t)row * ldc + col] = v;
        if (Ch) Ch[(size_t)row * ldc + col] = (_Float16)v;
      }
}

// ============== pv_exp: 128x128 GEMM, A = exp(S - m[row]) * mask (reg-staged) ==============
// C = P[M,K] * VT[N,K]^T partials; A staged via regs (load raw f16 score -> masked
// exp -> ds_write to the SAME swizzled layout gld_lds would produce); B via gld_lds.
__global__ __launch_bounds__(256)
void pv_exp(const _Float16* __restrict__ S, const _Float16* __restrict__ VT,
            const uint32_t* __restrict__ bits, const float* __restrict__ mrow,
            _Float16* __restrict__ Pk, int Kc, long MN)
{
  __shared__ _Float16 As[128][32];
  __shared__ _Float16 Bs[128][32];
  const int tid = threadIdx.x;
  const int wave = tid >> 6, lane = tid & 63;
  const int wr = wave >> 1, wc = wave & 1;
  const int row0 = blockIdx.x * 128, col0 = blockIdx.y * 128;
  const int kbase = blockIdx.z * Kc;

  const int sr = lane >> 2;                              // row in 16-row group
  const int lsl = (lane & 3) ^ ((lane >> 3) & 3);        // logical 16B slot to fetch
  const int psl = lane & 3;                              // physical slot to write

  // hoisted per-c row state (k-invariant)
  int arow[2]; float mv[2]; const uint32_t* brow[2]; size_t sbase[2];
  #pragma unroll
  for (int c = 0; c < 2; ++c) {
    arow[c] = row0 + c * 64 + wave * 16 + sr;
    mv[c] = mrow[arow[c]];
    brow[c] = bits + (size_t)arow[c] * 192;
    sbase[c] = (size_t)arow[c] * NROW + kbase + lsl * 8;
  }

  f32x4 acc[4][4];
  const f32x4 vzero = {0.f, 0.f, 0.f, 0.f};
  #pragma unroll
  for (int i = 0; i < 4; ++i)
    #pragma unroll
    for (int j = 0; j < 4; ++j)
      acc[i][j] = vzero;

  const int fr = lane & 15;
  const int fk = (((lane >> 4) ^ ((fr >> 1) & 3))) * 8;

  for (int k0 = 0; k0 < Kc; k0 += 32) {
    // B via async gld_lds (pre-swizzled global source)
    #pragma unroll
    for (int c = 0; c < 2; ++c) {
      int rbase = c * 64 + wave * 16;
      gld_lds16(&Bs[rbase][0], VT + (size_t)(col0 + rbase + sr) * NROW + kbase + k0 + lsl * 8);
    }
    // A reg-staged: raw score -> masked exp -> f16 -> ds_write (swizzled layout)
    #pragma unroll
    for (int c = 0; c < 2; ++c) {
      int kv = kbase + k0 + lsl * 8;
      half8 sv = *(const half8*)&S[sbase[c] + k0];
      uint32_t w = (brow[c][kv >> 5] >> (kv & 31)) & 0xffu;
      half8 pvv;
      #pragma unroll
      for (int e = 0; e < 8; ++e)
        pvv[e] = (_Float16)(((w >> e) & 1u) ? __expf((float)sv[e] - mv[c]) : 0.f);
      *(half8*)&As[c * 64 + wave * 16 + sr][psl * 8] = pvv;
    }
    __syncthreads();
    half8 af[4], bf[4];
    #pragma unroll
    for (int i = 0; i < 4; ++i)
      af[i] = *(const half8*)&As[wr * 64 + i * 16 + fr][fk];
    #pragma unroll
    for (int j = 0; j < 4; ++j)
      bf[j] = *(const half8*)&Bs[wc * 64 + j * 16 + fr][fk];
    #pragma unroll
    for (int i = 0; i < 4; ++i)
      #pragma unroll
      for (int j = 0; j < 4; ++j)
        acc[i][j] = __builtin_amdgcn_mfma_f32_16x16x32_f16(af[i], bf[j], acc[i][j], 0, 0, 0);
    __syncthreads();
  }

  const int lr = (lane >> 4) * 4;
  const int lc = lane & 15;
  _Float16* dst = Pk + (size_t)blockIdx.z * MN;
  #pragma unroll
  for (int i = 0; i < 4; ++i)
    #pragma unroll
    for (int j = 0; j < 4; ++j)
      #pragma unroll
      for (int r = 0; r < 4; ++r) {
        int row = row0 + wr * 64 + i * 16 + lr + r;
        int col = col0 + wc * 64 + j * 16 + lc;
        dst[(size_t)row * 512 + col] = (_Float16)acc[i][j][r];
      }
}

// ---------------- split-K reduce: Y = rowscale(row) * sum_z Pk[z]; writes f32/f16
__global__ __launch_bounds__(256)
void reduce_splitk(const _Float16* __restrict__ Pk, long MN, int S, int cshift,
                   const float* __restrict__ rowscale,
                   float* __restrict__ Yf, _Float16* __restrict__ Yh)
{
  long n4 = MN >> 2;
  for (long i = (long)blockIdx.x * 256 + threadIdx.x; i < n4; i += (long)gridDim.x * 256) {
    float s0 = 0, s1 = 0, s2 = 0, s3 = 0;
    for (int z = 0; z < S; ++z) {
      half4v p = ((const half4v*)(Pk + (size_t)z * MN))[i];
      s0 += (float)p[0]; s1 += (float)p[1]; s2 += (float)p[2]; s3 += (float)p[3];
    }
    if (rowscale) {
      float sc = rowscale[(i * 4) >> cshift];
      s0 *= sc; s1 *= sc; s2 *= sc; s3 *= sc;
    }
    if (Yf) {
      float4 o; o.x = s0; o.y = s1; o.z = s2; o.w = s3;
      ((float4*)Yf)[i] = o;
    }
    if (Yh) {
      half4v o;
      o[0] = (_Float16)s0; o[1] = (_Float16)s1; o[2] = (_Float16)s2; o[3] = (_Float16)s3;
      ((half4v*)Yh)[i] = o;
    }
  }
}

// ---------------- fused: degree row-sum -> dis, and f32 -> f16 adjacency convert
__global__ __launch_bounds__(256)
void degree_convert(const float* __restrict__ A, _Float16* __restrict__ Ah,
                    float* __restrict__ dis)
{
  const int row = blockIdx.x;
  const float* a = A + (size_t)row * NROW;
  _Float16* o = Ah + (size_t)row * NROW;
  float s = 0.f;
  #pragma unroll
  for (int it = 0; it < 6; ++it) {
    int j = it * 1024 + threadIdx.x * 4;
    float4 v = *(const float4*)&a[j];
    s += v.x + v.y + v.z + v.w;
    half4v h;
    h[0] = (_Float16)v.x; h[1] = (_Float16)v.y; h[2] = (_Float16)v.z; h[3] = (_Float16)v.w;
    *(half4v*)&o[j] = h;
  }
  #pragma unroll
  for (int off = 32; off; off >>= 1) s += __shfl_xor(s, off);
  __shared__ float red[4];
  if ((threadIdx.x & 63) == 0) red[threadIdx.x >> 6] = s;
  __syncthreads();
  if (threadIdx.x == 0) {
    float d = red[0] + red[1] + red[2] + red[3];
    dis[row] = (d > 0.f) ? rsqrtf(fmaxf(d, 1e-12f)) : 0.f;
  }
}

// ---------------- adj (f32 0/1) -> bitmask [NROW][192] u32
__global__ __launch_bounds__(192)
void build_mask(const float* __restrict__ adj, uint32_t* __restrict__ bits)
{
  const int row = blockIdx.x;
  const int w = threadIdx.x;
  const float* a = adj + (size_t)row * NROW + w * 32;
  uint32_t m = 0;
  #pragma unroll
  for (int q = 0; q < 8; ++q) {
    float4 x = *(const float4*)&a[q * 4];
    m |= (x.x != 0.f ? 1u : 0u) << (q * 4 + 0);
    m |= (x.y != 0.f ? 1u : 0u) << (q * 4 + 1);
    m |= (x.z != 0.f ? 1u : 0u) << (q * 4 + 2);
    m |= (x.w != 0.f ? 1u : 0u) << (q * 4 + 3);
  }
  bits[(size_t)row * 192 + w] = m;
}

// ---------------- one-shot weight conversion: 13 segments in a single launch
struct WConv {
  const float* src[13];
  _Float16* dst[13];
  int n4[13];
  float scale[13];
};
__global__ __launch_bounds__(256)
void convert_weights(WConv w)
{
  const int seg = blockIdx.x >> 4;          // 16 blocks per segment
  const int bi = blockIdx.x & 15;
  const float* x = w.src[seg];
  _Float16* y = w.dst[seg];
  const float sc = w.scale[seg];
  const int n4 = w.n4[seg];
  for (int i = bi * 256 + threadIdx.x; i < n4; i += 16 * 256) {
    float4 v = ((const float4*)x)[i];
    half4v o;
    o[0] = (_Float16)(v.x * sc); o[1] = (_Float16)(v.y * sc);
    o[2] = (_Float16)(v.z * sc); o[3] = (_Float16)(v.w * sc);
    ((half4v*)y)[i] = o;
  }
}

// ---------------- dst[c][r] = f16(src[r][c] * rowscale[r]); src f32 [R,C], dst [C,R]
__global__ __launch_bounds__(256)
void transpose_scale_f16(const float* __restrict__ src, const float* __restrict__ rowscale,
                         _Float16* __restrict__ dst, int R, int C)
{
  __shared__ _Float16 tile[64][72];
  const int c0 = blockIdx.x * 64, r0 = blockIdx.y * 64;
  const int tx4 = (threadIdx.x & 15) * 4, ty = threadIdx.x >> 4;
  #pragma unroll
  for (int p = 0; p < 4; ++p) {
    int r = p * 16 + ty;
    float4 v = *(const float4*)&src[(size_t)(r0 + r) * C + c0 + tx4];
    float sc = rowscale ? rowscale[r0 + r] : 1.0f;
    tile[tx4 + 0][r] = (_Float16)(v.x * sc);
    tile[tx4 + 1][r] = (_Float16)(v.y * sc);
    tile[tx4 + 2][r] = (_Float16)(v.z * sc);
    tile[tx4 + 3][r] = (_Float16)(v.w * sc);
  }
  __syncthreads();
  #pragma unroll
  for (int p = 0; p < 4; ++p) {
    int c = p * 16 + ty;
    half4v o;
    o[0] = tile[c][tx4 + 0];
    o[1] = tile[c][tx4 + 1];
    o[2] = tile[c][tx4 + 2];
    o[3] = tile[c][tx4 + 3];
    *(half4v*)&dst[(size_t)(c0 + c) * R + r0 + tx4] = o;
  }
}

// ---------------- dst[c][r] = src[r*ld + c]; f16 -> f16 transpose
__global__ __launch_bounds__(256)
void transpose_f16(const _Float16* __restrict__ src, int ld,
                   _Float16* __restrict__ dst, int R, int C)
{
  __shared__ _Float16 tile[64][72];
  const int c0 = blockIdx.x * 64, r0 = blockIdx.y * 64;
  const int tx4 = (threadIdx.x & 15) * 4, ty = threadIdx.x >> 4;
  #pragma unroll
  for (int p = 0; p < 4; ++p) {
    int r = p * 16 + ty;
    half4v v = *(const half4v*)&src[(size_t)(r0 + r) * ld + c0 + tx4];
    tile[tx4 + 0][r] = v[0];
    tile[tx4 + 1][r] = v[1];
    tile[tx4 + 2][r] = v[2];
    tile[tx4 + 3][r] = v[3];
  }
  __syncthreads();
  #pragma unroll
  for (int p = 0; p < 4; ++p) {
    int c = p * 16 + ty;
    half4v o;
    o[0] = tile[c][tx4 + 0];
    o[1] = tile[c][tx4 + 1];
    o[2] = tile[c][tx4 + 2];
    o[3] = tile[c][tx4 + 3];
    *(half4v*)&dst[(size_t)(c0 + c) * R + r0 + tx4] = o;
  }
}

// ---------------- masked softmax STATS only: m[row], linv[row] (no S write-back)
__global__ __launch_bounds__(256)
void softmax_stats(const _Float16* __restrict__ Sf, const uint32_t* __restrict__ bits,
                   float* __restrict__ mrow, float* __restrict__ linv)
{
  const int row = blockIdx.x;
  const _Float16* s = Sf + (size_t)row * NROW;
  const uint32_t* b = bits + (size_t)row * 192;
  const int tid = threadIdx.x;
  float v[24];
  float m = NEG_INF;
  #pragma unroll
  for (int it = 0; it < 3; ++it) {
    int j = it * 2048 + tid * 8;
    half8 sv = *(const half8*)&s[j];
    uint32_t w = (b[j >> 5] >> (j & 31)) & 0xffu;
    #pragma unroll
    for (int e = 0; e < 8; ++e) {
      float x = ((w >> e) & 1u) ? (float)sv[e] : NEG_INF;
      v[it * 8 + e] = x;
      m = fmaxf(m, x);
    }
  }
  #pragma unroll
  for (int off = 32; off; off >>= 1) m = fmaxf(m, __shfl_xor(m, off));
  __shared__ float red[4];
  const int lane = tid & 63, wave = tid >> 6;
  if (lane == 0) red[wave] = m;
  __syncthreads();
  m = fmaxf(fmaxf(red[0], red[1]), fmaxf(red[2], red[3]));
  __syncthreads();
  float l = 0.f;
  #pragma unroll
  for (int k = 0; k < 24; ++k)
    l += (v[k] == NEG_INF) ? 0.f : __expf(v[k] - m);
  #pragma unroll
  for (int off = 32; off; off >>= 1) l += __shfl_xor(l, off);
  if (lane == 0) red[wave] = l;
  __syncthreads();
  if (tid == 0) {
    l = red[0] + red[1] + red[2] + red[3];
    mrow[row] = m;
    linv[row] = (l > 0.f) ? (1.f / l) : 0.f;
  }
}

// ---------------- BN partial sums, vectorized half8, 64 rows per block
__global__ __launch_bounds__(256)
void bn_partial(const _Float16* __restrict__ X, int C,
                float* __restrict__ psum, float* __restrict__ psq)
{
  const int b = blockIdx.x;
  const int t = threadIdx.x;
  const int tpc = C >> 3;            // 64 (C=512) or 32 (C=256)
  const int ng = 256 / tpc;          // 4 or 8 row groups
  const int g = t / tpc, c8 = (t % tpc) * 8;
  const int rpg = 64 / ng;
  const _Float16* x = X + (size_t)b * 64 * C;
  float s[8], q[8];
  #pragma unroll
  for (int e = 0; e < 8; ++e) { s[e] = 0.f; q[e] = 0.f; }
  for (int r = g * rpg; r < (g + 1) * rpg; ++r) {
    half8 v = *(const half8*)&x[(size_t)r * C + c8];
    #pragma unroll
    for (int e = 0; e < 8; ++e) {
      float f = (float)v[e];
      s[e] += f; q[e] += f * f;
    }
  }
  __shared__ float ls[256][8], lq[256][8];
  #pragma unroll
  for (int e = 0; e < 8; ++e) { ls[t][e] = s[e]; lq[t][e] = q[e]; }
  __syncthreads();
  for (int u = t; u < C; u += 256) {
    float ss = 0, qq = 0;
    for (int gg = 0; gg < ng; ++gg) {
      ss += ls[gg * tpc + (u >> 3)][u & 7];
      qq += lq[gg * tpc + (u >> 3)][u & 7];
    }
    psum[b * C + u] = ss; psq[b * C + u] = qq;
  }
}

__global__ void bn_finalize(const float* __restrict__ psum, const float* __restrict__ psq,
                            int C, const float* __restrict__ g, const float* __restrict__ beta,
                            float* __restrict__ scale, float* __restrict__ shift)
{
  int c = threadIdx.x + blockIdx.x * blockDim.x;
  if (c >= C) return;
  float s = 0, q = 0;
  for (int b = 0; b < 96; ++b) { s += psum[b * C + c]; q += psq[b * C + c]; }
  const float invN = 1.0f / 6144.0f;
  float mean = s * invN;
  float var = q * invN - mean * mean;
  float rstd = rsqrtf(fmaxf(var, 0.f) + 1e-5f);
  float sc = g[c] * rstd;
  scale[c] = sc;
  shift[c] = beta[c] - mean * sc;
}

// ---------------- y = relu?(x*scale[c]+shift[c]) + residual(f16); f16 input
__global__ __launch_bounds__(256)
void bn_apply(const _Float16* __restrict__ X, const float* __restrict__ scale,
              const float* __restrict__ shift, const _Float16* __restrict__ residual,
              float* __restrict__ Yf, _Float16* __restrict__ Yh,
              int Cmask, long total, int do_relu)
{
  for (long i = (long)blockIdx.x * 256 + threadIdx.x; i < total; i += (long)gridDim.x * 256) {
    int c = (int)(i & Cmask);
    float v = (float)X[i] * scale[c] + shift[c];
    if (do_relu) v = fmaxf(v, 0.f);
    if (residual) v += (float)residual[i];
    if (Yf) Yf[i] = v;
    if (Yh) Yh[i] = (_Float16)v;
  }
}

extern "C" void kernel_launch(void* const* d_in, const int* in_sizes, int n_in,
                              void* d_out, int out_size, void* d_ws, size_t ws_size,
                              hipStream_t stream)
{
  (void)in_sizes; (void)n_in; (void)out_size; (void)ws_size;
  const float* X     = (const float*)d_in[0];
  const float* adj   = (const float*)d_in[1];
  const float* adjg  = (const float*)d_in[2];
  const float* Wp    = (const float*)d_in[3];
  const float* gp    = (const float*)d_in[5];
  const float* betap = (const float*)d_in[6];

  float* out_h     = (float*)d_out;                       // [6144,256]
  float* out_embed = out_h + (size_t)NROW * DOUT;         // [6144,512]

  char* base = (char*)d_ws;
  size_t off = 0;
  auto alloc = [&](size_t bytes) -> void* {
    void* p = base + off;
    off += (bytes + 255) & ~(size_t)255;
    return p;
  };

  const long MN512 = (long)NROW * 512;

  _Float16* Ag  = (_Float16*)alloc((size_t)NROW * NROW * 2);   // adjg f16; reused as scores Sf
  _Float16* Sf  = Ag;
  uint32_t* bits = (uint32_t*)alloc((size_t)NROW * 192 * 4);
  _Float16* Pk  = (_Float16*)alloc((size_t)8 * MN512 * 2);     // split-K partials (f16)
  _Float16* XsT = (_Float16*)alloc((size_t)HDIM * NROW * 2);
  _Float16* Yh16 = (_Float16*)alloc((size_t)NROW * HDIM * 2);
  _Float16* Wph = (_Float16*)alloc((size_t)HDIM * HDIM * 2);
  _Float16* QKVW[3];
  for (int i = 0; i < 3; ++i) QKVW[i] = (_Float16*)alloc((size_t)1536 * HDIM * 2);
  _Float16* Woh[3];
  Woh[0] = (_Float16*)alloc((size_t)512 * 512 * 2);
  Woh[1] = (_Float16*)alloc((size_t)512 * 512 * 2);
  Woh[2] = (_Float16*)alloc((size_t)256 * 512 * 2);
  _Float16* QKVh = (_Float16*)alloc((size_t)NROW * 1536 * 2);
  _Float16* VTh  = (_Float16*)alloc((size_t)HDIM * NROW * 2);
  _Float16* AVh  = (_Float16*)alloc((size_t)NROW * HDIM * 2);
  _Float16* xh   = (_Float16*)alloc((size_t)NROW * HDIM * 2);  // pre-BN buffer (f16)
  _Float16* hb16A = (_Float16*)alloc((size_t)NROW * HDIM * 2);
  _Float16* hb16B = (_Float16*)alloc((size_t)NROW * HDIM * 2);
  float* dis  = (float*)alloc((size_t)NROW * 4);
  float* mrow = (float*)alloc((size_t)NROW * 4);
  float* linv = (float*)alloc((size_t)NROW * 4);
  float* psum = (float*)alloc((size_t)96 * 512 * 4);
  float* psq  = (float*)alloc((size_t)96 * 512 * 4);
  float* bnsc = (float*)alloc(512 * 4);
  float* bnsh = (float*)alloc(512 * 4);

  const float qk_scale = 0.21022410381342863f;  // 512^(-1/4); folded into both Wq and Wk

  degree_convert<<<NROW, 256, 0, stream>>>(adjg, Ag, dis);
  build_mask<<<NROW, 192, 0, stream>>>(adj, bits);
  transpose_scale_f16<<<dim3(8, 96), 256, 0, stream>>>(X, dis, XsT, NROW, HDIM);

  {
    WConv w;
    int seg = 0;
    w.src[seg] = Wp; w.dst[seg] = Wph; w.n4[seg] = 512 * 512 / 4; w.scale[seg] = 1.f; ++seg;
    for (int i = 0; i < 3; ++i) {
      int o = (i < 2) ? 512 : 256;
      w.src[seg] = (const float*)d_in[7 + i * 7 + 0]; w.dst[seg] = QKVW[i];
      w.n4[seg] = 512 * 512 / 4; w.scale[seg] = qk_scale; ++seg;
      w.src[seg] = (const float*)d_in[7 + i * 7 + 1]; w.dst[seg] = QKVW[i] + 512 * 512;
      w.n4[seg] = 512 * 512 / 4; w.scale[seg] = qk_scale; ++seg;
      w.src[seg] = (const float*)d_in[7 + i * 7 + 2]; w.dst[seg] = QKVW[i] + 2 * 512 * 512;
      w.n4[seg] = 512 * 512 / 4; w.scale[seg] = 1.f; ++seg;
      w.src[seg] = (const float*)d_in[7 + i * 7 + 3]; w.dst[seg] = Woh[i];
      w.n4[seg] = o * 512 / 4; w.scale[seg] = 1.f; ++seg;
    }
    convert_weights<<<13 * 16, 256, 0, stream>>>(w);
  }

  // ---- embedding: h = BN( rowscale(dis) * (Ag @ XsT^T) @ Wp^T )   (bias cancels in BN)
  gemm256<<<dim3(24, 2, 8), 512, 0, stream>>>(Ag, NROW, XsT, NROW, Pk, 512, 768, MN512);
  reduce_splitk<<<1536, 256, 0, stream>>>(Pk, MN512, 8, 9, dis, nullptr, Yh16);
  gemm_f16<<<dim3(48, 4), 256, 0, stream>>>(Yh16, HDIM, Wph, HDIM, nullptr, xh, HDIM,
                                            512, nullptr, 0);
  bn_partial<<<96, 256, 0, stream>>>(xh, 512, psum, psq);
  bn_finalize<<<2, 256, 0, stream>>>(psum, psq, 512, gp, betap, bnsc, bnsh);
  bn_apply<<<2048, 256, 0, stream>>>(xh, bnsc, bnsh, nullptr, out_embed, hb16A,
                                     511, MN512, 0);

  _Float16* hbuf[2] = {hb16A, hb16B};
  int cur = 0;
  for (int i = 0; i < 3; ++i) {
    int o = (i < 2) ? 512 : 256;
    const float* gl = (const float*)d_in[7 + i * 7 + 5];
    const float* bl = (const float*)d_in[7 + i * 7 + 6];
    _Float16* hin = hbuf[cur];

    // fused QKV projection: [6144,1536]
    gemm_f16<<<dim3(48, 12), 256, 0, stream>>>(hin, HDIM, QKVW[i], HDIM, nullptr, QKVh, 1536,
                                               512, nullptr, 0);
    transpose_f16<<<dim3(8, 96), 256, 0, stream>>>(QKVh + 1024, 1536, VTh, NROW, HDIM);
    // raw scores (f16), then stats (m, 1/l) only
    gemm256<<<dim3(24, 24), 512, 0, stream>>>(QKVh, 1536, QKVh + 512, 1536, Sf, NROW, 512, 0);
    softmax_stats<<<NROW, 256, 0, stream>>>(Sf, bits, mrow, linv);
    // attn @ V with exp+mask applied during A staging (split-K 8); 1/l in reduce
    pv_exp<<<dim3(48, 4, 8), 256, 0, stream>>>(Sf, VTh, bits, mrow, Pk, 768, MN512);
    reduce_splitk<<<1536, 256, 0, stream>>>(Pk, MN512, 8, 9, linv, nullptr, AVh);
    // @ Wo^T (split-K 4; bias cancels in BN)
    long MNo = (long)NROW * o;
    gemm_f16<<<dim3(48, o / 128, 4), 256, 0, stream>>>(AVh, HDIM, Woh[i], HDIM,
                                                       nullptr, nullptr, o, 128, Pk, MNo);
    reduce_splitk<<<1536, 256, 0, stream>>>(Pk, MNo, 4, (o == 512) ? 9 : 8, nullptr,
                                            nullptr, xh);
    bn_partial<<<96, 256, 0, stream>>>(xh, o, psum, psq);
    bn_finalize<<<2, 256, 0, stream>>>(psum, psq, o, gl, bl, bnsc, bnsh);
    if (i < 2) {
      bn_apply<<<2048, 256, 0, stream>>>(xh, bnsc, bnsh, hin, nullptr, hbuf[cur ^ 1],
                                         o - 1, (long)NROW * o, 1);
      cur ^= 1;
    } else {
      bn_apply<<<2048, 256, 0, stream>>>(xh, bnsc, bnsh, nullptr, out_h, nullptr,
                                         o - 1, (long)NROW * o, 1);
    }
  }
}

// Round 7
// 834.738 us; speedup vs baseline: 1.2405x; 1.0796x over previous
//
#include <hip/hip_runtime.h>
#include <cstdint>

#define NROW 6144
#define HDIM 512
#define DOUT 256
#define NEG_INF (-__builtin_inff())

typedef _Float16 half8 __attribute__((ext_vector_type(8)));
typedef _Float16 half4v __attribute__((ext_vector_type(4)));
typedef float f32x4 __attribute__((ext_vector_type(4)));

#define BARRIER() asm volatile("s_barrier" ::: "memory")
#define LGKM0()   asm volatile("s_waitcnt lgkmcnt(0)" ::: "memory")
#define VMCNT4()  asm volatile("s_waitcnt vmcnt(4)" ::: "memory")
#define VMCNT0()  asm volatile("s_waitcnt vmcnt(0)" ::: "memory")

__device__ __forceinline__ void gld_lds16(void* lds, const void* g) {
  __builtin_amdgcn_global_load_lds(
      (const __attribute__((address_space(1))) void*)g,
      (__attribute__((address_space(3))) void*)lds, 16, 0, 0);
}

// ============== gemm256: 8-phase 256x256 GEMM (proven round-5/6 schedule) ==============
// C[M,N] = A[M,K] * B[N,K]^T (row-major, f16 in, f32 acc, f16 out). Stage ledger:
// ph1 A(1,h0,T+1) ph2 A(1,h1,T+1) ph3 B(0,h0,T+2) ph4 B(0,h1,T+2)
// ph5 A(0,h0,T+2) ph6 A(0,h1,T+2) ph7 B(1,h0,T+3) ph8 B(1,h1,T+3); vmcnt(4) at
// ph4/ph8; tail vmcnt(0). LDS swizzle: 16B slot s of row r holds logical s^(r&7).
__global__ __launch_bounds__(512, 2)
void gemm256(const _Float16* __restrict__ A, int lda,
             const _Float16* __restrict__ B, int ldb,
             _Float16* __restrict__ C, int ldc, int Kc, long MN)
{
  __shared__ _Float16 As[2][256][64];
  __shared__ _Float16 Bs[2][256][64];
  const int tid = threadIdx.x;
  const int wave = tid >> 6, lane = tid & 63;
  const int wr = wave >> 2, wc = wave & 3;            // 2 x 4 wave grid

  const int gx = gridDim.x, gy = gridDim.y;
  const int nwg = gx * gy * gridDim.z;
  int lin = (blockIdx.z * gy + blockIdx.y) * gx + blockIdx.x;
  int swz = (nwg % 8 == 0) ? ((lin % 8) * (nwg >> 3) + (lin >> 3)) : lin;
  const int bx = swz % gx, by = (swz / gx) % gy, bz = swz / (gx * gy);
  const int row0 = bx * 256, col0 = by * 256;
  const _Float16* Ab = A + (size_t)row0 * lda + (size_t)bz * Kc;
  const _Float16* Bb = B + (size_t)col0 * ldb + (size_t)bz * Kc;
  const int nt = Kc >> 6;                             // K-tiles of 64 (even)

  const int srow = lane >> 3;
  const int sgr  = (lane & 7) ^ srow;                 // pre-swizzled src 16B granule

  auto stageA = [&](int buf, int h, int t) {
    const _Float16* src = Ab + (size_t)(h * 128 + wave * 8 + srow) * lda + t * 64 + sgr * 8;
    gld_lds16(&As[buf][h * 128 + wave * 8][0], src);
    gld_lds16(&As[buf][h * 128 + 64 + wave * 8][0], src + (size_t)64 * lda);
  };
  auto stageB = [&](int buf, int h, int t) {
    const _Float16* src = Bb + (size_t)(h * 128 + wave * 8 + srow) * ldb + t * 64 + sgr * 8;
    gld_lds16(&Bs[buf][h * 128 + wave * 8][0], src);
    gld_lds16(&Bs[buf][h * 128 + 64 + wave * 8][0], src + (size_t)64 * ldb);
  };

  const int fr = lane & 15, sq = lane >> 4, fx = fr & 7;
  half8 af[4][2], bLo[2][2], bHi[2][2];
  f32x4 acc[8][4];
  const f32x4 vzero = {0.f, 0.f, 0.f, 0.f};
  #pragma unroll
  for (int f = 0; f < 8; ++f)
    #pragma unroll
    for (int j = 0; j < 4; ++j)
      acc[f][j] = vzero;

  auto dsA = [&](int buf, int mh) {
    #pragma unroll
    for (int i = 0; i < 4; ++i)
      #pragma unroll
      for (int ks = 0; ks < 2; ++ks)
        af[i][ks] = *(const half8*)&As[buf][wr * 128 + mh * 64 + i * 16 + fr]
                                          [((ks * 4 + sq) ^ fx) * 8];
  };
  auto dsBlo = [&](int buf) {
    #pragma unroll
    for (int jj = 0; jj < 2; ++jj)
      #pragma unroll
      for (int ks = 0; ks < 2; ++ks)
        bLo[jj][ks] = *(const half8*)&Bs[buf][wc * 64 + jj * 16 + fr]
                                            [((ks * 4 + sq) ^ fx) * 8];
  };
  auto dsBhi = [&](int buf) {
    #pragma unroll
    for (int jj = 0; jj < 2; ++jj)
      #pragma unroll
      for (int ks = 0; ks < 2; ++ks)
        bHi[jj][ks] = *(const half8*)&Bs[buf][wc * 64 + 32 + jj * 16 + fr]
                                            [((ks * 4 + sq) ^ fx) * 8];
  };
  auto mQlo = [&](int fb) {
    __builtin_amdgcn_s_setprio(1);
    #pragma unroll
    for (int i = 0; i < 4; ++i)
      #pragma unroll
      for (int jj = 0; jj < 2; ++jj)
        #pragma unroll
        for (int ks = 0; ks < 2; ++ks)
          acc[fb + i][jj] = __builtin_amdgcn_mfma_f32_16x16x32_f16(
              af[i][ks], bLo[jj][ks], acc[fb + i][jj], 0, 0, 0);
    __builtin_amdgcn_s_setprio(0);
  };
  auto mQhi = [&](int fb) {
    __builtin_amdgcn_s_setprio(1);
    #pragma unroll
    for (int i = 0; i < 4; ++i)
      #pragma unroll
      for (int jj = 0; jj < 2; ++jj)
        #pragma unroll
        for (int ks = 0; ks < 2; ++ks)
          acc[fb + i][2 + jj] = __builtin_amdgcn_mfma_f32_16x16x32_f16(
              af[i][ks], bHi[jj][ks], acc[fb + i][2 + jj], 0, 0, 0);
    __builtin_amdgcn_s_setprio(0);
  };

  stageA(0, 0, 0); stageA(0, 1, 0); stageB(0, 0, 0); stageB(0, 1, 0);
  stageB(1, 0, 1); stageB(1, 1, 1);
  VMCNT4();
  BARRIER();

  for (int T = 0; T < nt; T += 2) {
    const bool pipe = (T + 2 < nt);
    dsA(0, 0); dsBlo(0);
    stageA(1, 0, T + 1);
    BARRIER(); LGKM0(); mQlo(0); BARRIER();
    dsBhi(0);
    stageA(1, 1, T + 1);
    BARRIER(); LGKM0(); mQhi(0); BARRIER();
    dsA(0, 1);
    if (pipe) stageB(0, 0, T + 2);
    BARRIER(); LGKM0(); mQhi(4); BARRIER();
    if (pipe) { stageB(0, 1, T + 2); VMCNT4(); } else { VMCNT0(); }
    BARRIER(); mQlo(4); BARRIER();
    dsA(1, 0); dsBlo(1);
    if (pipe) stageA(0, 0, T + 2);
    BARRIER(); LGKM0(); mQlo(0); BARRIER();
    dsBhi(1);
    if (pipe) stageA(0, 1, T + 2);
    BARRIER(); LGKM0(); mQhi(0); BARRIER();
    dsA(1, 1);
    if (pipe) stageB(1, 0, T + 3);
    BARRIER(); LGKM0(); mQhi(4); BARRIER();
    if (pipe) { stageB(1, 1, T + 3); VMCNT4(); } else { VMCNT0(); }
    BARRIER(); mQlo(4); BARRIER();
  }

  _Float16* dst = C + (size_t)bz * MN;
  #pragma unroll
  for (int f = 0; f < 8; ++f)
    #pragma unroll
    for (int j = 0; j < 4; ++j)
      #pragma unroll
      for (int r = 0; r < 4; ++r) {
        int row = row0 + wr * 128 + f * 16 + sq * 4 + r;
        int col = col0 + wc * 64 + j * 16 + fr;
        dst[(size_t)row * ldc + col] = (_Float16)acc[f][j][r];
      }
}

// ================= 128x128 GEMM (m97 structure) for the small-N GEMMs =================
__global__ __launch_bounds__(256)
void gemm_f16(const _Float16* __restrict__ A, int lda,
              const _Float16* __restrict__ B, int ldb,
              float* __restrict__ Cf, _Float16* __restrict__ Ch, int ldc,
              int Kc, _Float16* __restrict__ Pk, long MN)
{
  __shared__ _Float16 As[128][32];
  __shared__ _Float16 Bs[128][32];
  const int tid = threadIdx.x;
  const int wave = tid >> 6, lane = tid & 63;
  const int wr = wave >> 1, wc = wave & 1;
  const int row0 = blockIdx.x * 128, col0 = blockIdx.y * 128;
  const int kbase = blockIdx.z * Kc;

  const int sr = lane >> 2;
  const int sk = ((lane & 3) ^ ((lane >> 3) & 3)) * 8;

  f32x4 acc[4][4];
  const f32x4 vzero = {0.f, 0.f, 0.f, 0.f};
  #pragma unroll
  for (int i = 0; i < 4; ++i)
    #pragma unroll
    for (int j = 0; j < 4; ++j)
      acc[i][j] = vzero;

  const int fr = lane & 15;
  const int fk = (((lane >> 4) ^ ((fr >> 1) & 3))) * 8;

  for (int k0 = kbase; k0 < kbase + Kc; k0 += 32) {
    #pragma unroll
    for (int c = 0; c < 2; ++c) {
      int rbase = c * 64 + wave * 16;
      gld_lds16(&As[rbase][0], A + (size_t)(row0 + rbase + sr) * lda + k0 + sk);
      gld_lds16(&Bs[rbase][0], B + (size_t)(col0 + rbase + sr) * ldb + k0 + sk);
    }
    __syncthreads();
    half8 af[4], bf[4];
    #pragma unroll
    for (int i = 0; i < 4; ++i)
      af[i] = *(const half8*)&As[wr * 64 + i * 16 + fr][fk];
    #pragma unroll
    for (int j = 0; j < 4; ++j)
      bf[j] = *(const half8*)&Bs[wc * 64 + j * 16 + fr][fk];
    #pragma unroll
    for (int i = 0; i < 4; ++i)
      #pragma unroll
      for (int j = 0; j < 4; ++j)
        acc[i][j] = __builtin_amdgcn_mfma_f32_16x16x32_f16(af[i], bf[j], acc[i][j], 0, 0, 0);
    __syncthreads();
  }

  const int lr = (lane >> 4) * 4;
  const int lc = lane & 15;
  if (Pk) {
    _Float16* dst = Pk + (size_t)blockIdx.z * MN;
    #pragma unroll
    for (int i = 0; i < 4; ++i)
      #pragma unroll
      for (int j = 0; j < 4; ++j)
        #pragma unroll
        for (int r = 0; r < 4; ++r) {
          int row = row0 + wr * 64 + i * 16 + lr + r;
          int col = col0 + wc * 64 + j * 16 + lc;
          dst[(size_t)row * ldc + col] = (_Float16)acc[i][j][r];
        }
    return;
  }
  #pragma unroll
  for (int i = 0; i < 4; ++i)
    #pragma unroll
    for (int j = 0; j < 4; ++j)
      #pragma unroll
      for (int r = 0; r < 4; ++r) {
        int row = row0 + wr * 64 + i * 16 + lr + r;
        int col = col0 + wc * 64 + j * 16 + lc;
        float v = acc[i][j][r];
        if (Cf) Cf[(size_t)row * ldc + col] = v;
        if (Ch) Ch[(size_t)row * ldc + col] = (_Float16)v;
      }
}

// ---------------- split-K reduce: Y = rowscale(row) * sum_z Pk[z]; writes f32/f16
__global__ __launch_bounds__(256)
void reduce_splitk(const _Float16* __restrict__ Pk, long MN, int S, int cshift,
                   const float* __restrict__ rowscale,
                   float* __restrict__ Yf, _Float16* __restrict__ Yh)
{
  long n4 = MN >> 2;
  for (long i = (long)blockIdx.x * 256 + threadIdx.x; i < n4; i += (long)gridDim.x * 256) {
    float s0 = 0, s1 = 0, s2 = 0, s3 = 0;
    for (int z = 0; z < S; ++z) {
      half4v p = ((const half4v*)(Pk + (size_t)z * MN))[i];
      s0 += (float)p[0]; s1 += (float)p[1]; s2 += (float)p[2]; s3 += (float)p[3];
    }
    if (rowscale) {
      float sc = rowscale[(i * 4) >> cshift];
      s0 *= sc; s1 *= sc; s2 *= sc; s3 *= sc;
    }
    if (Yf) {
      float4 o; o.x = s0; o.y = s1; o.z = s2; o.w = s3;
      ((float4*)Yf)[i] = o;
    }
    if (Yh) {
      half4v o;
      o[0] = (_Float16)s0; o[1] = (_Float16)s1; o[2] = (_Float16)s2; o[3] = (_Float16)s3;
      ((half4v*)Yh)[i] = o;
    }
  }
}

// ---------------- fused: degree row-sum -> dis, and f32 -> f16 adjacency convert
__global__ __launch_bounds__(256)
void degree_convert(const float* __restrict__ A, _Float16* __restrict__ Ah,
                    float* __restrict__ dis)
{
  const int row = blockIdx.x;
  const float* a = A + (size_t)row * NROW;
  _Float16* o = Ah + (size_t)row * NROW;
  float s = 0.f;
  #pragma unroll
  for (int it = 0; it < 6; ++it) {
    int j = it * 1024 + threadIdx.x * 4;
    float4 v = *(const float4*)&a[j];
    s += v.x + v.y + v.z + v.w;
    half4v h;
    h[0] = (_Float16)v.x; h[1] = (_Float16)v.y; h[2] = (_Float16)v.z; h[3] = (_Float16)v.w;
    *(half4v*)&o[j] = h;
  }
  #pragma unroll
  for (int off = 32; off; off >>= 1) s += __shfl_xor(s, off);
  __shared__ float red[4];
  if ((threadIdx.x & 63) == 0) red[threadIdx.x >> 6] = s;
  __syncthreads();
  if (threadIdx.x == 0) {
    float d = red[0] + red[1] + red[2] + red[3];
    dis[row] = (d > 0.f) ? rsqrtf(fmaxf(d, 1e-12f)) : 0.f;
  }
}

// ---------------- adj (f32 0/1) -> bitmask [NROW][192] u32
__global__ __launch_bounds__(192)
void build_mask(const float* __restrict__ adj, uint32_t* __restrict__ bits)
{
  const int row = blockIdx.x;
  const int w = threadIdx.x;
  const float* a = adj + (size_t)row * NROW + w * 32;
  uint32_t m = 0;
  #pragma unroll
  for (int q = 0; q < 8; ++q) {
    float4 x = *(const float4*)&a[q * 4];
    m |= (x.x != 0.f ? 1u : 0u) << (q * 4 + 0);
    m |= (x.y != 0.f ? 1u : 0u) << (q * 4 + 1);
    m |= (x.z != 0.f ? 1u : 0u) << (q * 4 + 2);
    m |= (x.w != 0.f ? 1u : 0u) << (q * 4 + 3);
  }
  bits[(size_t)row * 192 + w] = m;
}

// ---------------- one-shot weight conversion: 13 segments in a single launch
struct WConv {
  const float* src[13];
  _Float16* dst[13];
  int n4[13];
  float scale[13];
};
__global__ __launch_bounds__(256)
void convert_weights(WConv w)
{
  const int seg = blockIdx.x >> 4;          // 16 blocks per segment
  const int bi = blockIdx.x & 15;
  const float* x = w.src[seg];
  _Float16* y = w.dst[seg];
  const float sc = w.scale[seg];
  const int n4 = w.n4[seg];
  for (int i = bi * 256 + threadIdx.x; i < n4; i += 16 * 256) {
    float4 v = ((const float4*)x)[i];
    half4v o;
    o[0] = (_Float16)(v.x * sc); o[1] = (_Float16)(v.y * sc);
    o[2] = (_Float16)(v.z * sc); o[3] = (_Float16)(v.w * sc);
    ((half4v*)y)[i] = o;
  }
}

// ---------------- dst[c][r] = f16(src[r][c] * rowscale[r]); src f32 [R,C], dst [C,R]
__global__ __launch_bounds__(256)
void transpose_scale_f16(const float* __restrict__ src, const float* __restrict__ rowscale,
                         _Float16* __restrict__ dst, int R, int C)
{
  __shared__ _Float16 tile[64][72];
  const int c0 = blockIdx.x * 64, r0 = blockIdx.y * 64;
  const int tx4 = (threadIdx.x & 15) * 4, ty = threadIdx.x >> 4;
  #pragma unroll
  for (int p = 0; p < 4; ++p) {
    int r = p * 16 + ty;
    float4 v = *(const float4*)&src[(size_t)(r0 + r) * C + c0 + tx4];
    float sc = rowscale ? rowscale[r0 + r] : 1.0f;
    tile[tx4 + 0][r] = (_Float16)(v.x * sc);
    tile[tx4 + 1][r] = (_Float16)(v.y * sc);
    tile[tx4 + 2][r] = (_Float16)(v.z * sc);
    tile[tx4 + 3][r] = (_Float16)(v.w * sc);
  }
  __syncthreads();
  #pragma unroll
  for (int p = 0; p < 4; ++p) {
    int c = p * 16 + ty;
    half4v o;
    o[0] = tile[c][tx4 + 0];
    o[1] = tile[c][tx4 + 1];
    o[2] = tile[c][tx4 + 2];
    o[3] = tile[c][tx4 + 3];
    *(half4v*)&dst[(size_t)(c0 + c) * R + r0 + tx4] = o;
  }
}

// ---------------- dst[c][r] = src[r*ld + c]; f16 -> f16 transpose
__global__ __launch_bounds__(256)
void transpose_f16(const _Float16* __restrict__ src, int ld,
                   _Float16* __restrict__ dst, int R, int C)
{
  __shared__ _Float16 tile[64][72];
  const int c0 = blockIdx.x * 64, r0 = blockIdx.y * 64;
  const int tx4 = (threadIdx.x & 15) * 4, ty = threadIdx.x >> 4;
  #pragma unroll
  for (int p = 0; p < 4; ++p) {
    int r = p * 16 + ty;
    half4v v = *(const half4v*)&src[(size_t)(r0 + r) * ld + c0 + tx4];
    tile[tx4 + 0][r] = v[0];
    tile[tx4 + 1][r] = v[1];
    tile[tx4 + 2][r] = v[2];
    tile[tx4 + 3][r] = v[3];
  }
  __syncthreads();
  #pragma unroll
  for (int p = 0; p < 4; ++p) {
    int c = p * 16 + ty;
    half4v o;
    o[0] = tile[c][tx4 + 0];
    o[1] = tile[c][tx4 + 1];
    o[2] = tile[c][tx4 + 2];
    o[3] = tile[c][tx4 + 3];
    *(half4v*)&dst[(size_t)(c0 + c) * R + r0 + tx4] = o;
  }
}

// ---------------- in-place masked softmax over f16 scores; writes UNNORMALIZED exp
// and linv[row] = 1/sum (normalization folded into PV reduce rowscale)
__global__ __launch_bounds__(256)
void softmax_mask16(_Float16* __restrict__ Sf, const uint32_t* __restrict__ bits,
                    float* __restrict__ linv)
{
  const int row = blockIdx.x;
  _Float16* s = Sf + (size_t)row * NROW;
  const uint32_t* b = bits + (size_t)row * 192;
  const int tid = threadIdx.x;
  float v[24];
  float m = NEG_INF;
  #pragma unroll
  for (int it = 0; it < 3; ++it) {
    int j = it * 2048 + tid * 8;
    half8 sv = *(const half8*)&s[j];
    uint32_t w = (b[j >> 5] >> (j & 31)) & 0xffu;
    #pragma unroll
    for (int e = 0; e < 8; ++e) {
      float x = ((w >> e) & 1u) ? (float)sv[e] : NEG_INF;
      v[it * 8 + e] = x;
      m = fmaxf(m, x);
    }
  }
  #pragma unroll
  for (int off = 32; off; off >>= 1) m = fmaxf(m, __shfl_xor(m, off));
  __shared__ float red[4];
  const int lane = tid & 63, wave = tid >> 6;
  if (lane == 0) red[wave] = m;
  __syncthreads();
  m = fmaxf(fmaxf(red[0], red[1]), fmaxf(red[2], red[3]));
  __syncthreads();
  float l = 0.f;
  #pragma unroll
  for (int k = 0; k < 24; ++k) {
    float e = (v[k] == NEG_INF) ? 0.f : __expf(v[k] - m);
    v[k] = e; l += e;
  }
  #pragma unroll
  for (int off = 32; off; off >>= 1) l += __shfl_xor(l, off);
  if (lane == 0) red[wave] = l;
  __syncthreads();
  l = red[0] + red[1] + red[2] + red[3];
  if (tid == 0) linv[row] = (l > 0.f) ? (1.f / l) : 0.f;
  #pragma unroll
  for (int it = 0; it < 3; ++it) {
    int j = it * 2048 + tid * 8;
    half8 o;
    #pragma unroll
    for (int e = 0; e < 8; ++e) o[e] = (_Float16)v[it * 8 + e];
    *(half8*)&s[j] = o;
  }
}

// ---------------- BN partial sums, vectorized half8, 64 rows per block
__global__ __launch_bounds__(256)
void bn_partial(const _Float16* __restrict__ X, int C,
                float* __restrict__ psum, float* __restrict__ psq)
{
  const int b = blockIdx.x;
  const int t = threadIdx.x;
  const int tpc = C >> 3;            // 64 (C=512) or 32 (C=256)
  const int ng = 256 / tpc;          // 4 or 8 row groups
  const int g = t / tpc, c8 = (t % tpc) * 8;
  const int rpg = 64 / ng;
  const _Float16* x = X + (size_t)b * 64 * C;
  float s[8], q[8];
  #pragma unroll
  for (int e = 0; e < 8; ++e) { s[e] = 0.f; q[e] = 0.f; }
  for (int r = g * rpg; r < (g + 1) * rpg; ++r) {
    half8 v = *(const half8*)&x[(size_t)r * C + c8];
    #pragma unroll
    for (int e = 0; e < 8; ++e) {
      float f = (float)v[e];
      s[e] += f; q[e] += f * f;
    }
  }
  __shared__ float ls[256][8], lq[256][8];
  #pragma unroll
  for (int e = 0; e < 8; ++e) { ls[t][e] = s[e]; lq[t][e] = q[e]; }
  __syncthreads();
  for (int u = t; u < C; u += 256) {
    float ss = 0, qq = 0;
    for (int gg = 0; gg < ng; ++gg) {
      ss += ls[gg * tpc + (u >> 3)][u & 7];
      qq += lq[gg * tpc + (u >> 3)][u & 7];
    }
    psum[b * C + u] = ss; psq[b * C + u] = qq;
  }
}

__global__ void bn_finalize(const float* __restrict__ psum, const float* __restrict__ psq,
                            int C, const float* __restrict__ g, const float* __restrict__ beta,
                            float* __restrict__ scale, float* __restrict__ shift)
{
  int c = threadIdx.x + blockIdx.x * blockDim.x;
  if (c >= C) return;
  float s = 0, q = 0;
  for (int b = 0; b < 96; ++b) { s += psum[b * C + c]; q += psq[b * C + c]; }
  const float invN = 1.0f / 6144.0f;
  float mean = s * invN;
  float var = q * invN - mean * mean;
  float rstd = rsqrtf(fmaxf(var, 0.f) + 1e-5f);
  float sc = g[c] * rstd;
  scale[c] = sc;
  shift[c] = beta[c] - mean * sc;
}

// ---------------- y = relu?(x*scale[c]+shift[c]) + residual(f16); f16 input
__global__ __launch_bounds__(256)
void bn_apply(const _Float16* __restrict__ X, const float* __restrict__ scale,
              const float* __restrict__ shift, const _Float16* __restrict__ residual,
              float* __restrict__ Yf, _Float16* __restrict__ Yh,
              int Cmask, long total, int do_relu)
{
  for (long i = (long)blockIdx.x * 256 + threadIdx.x; i < total; i += (long)gridDim.x * 256) {
    int c = (int)(i & Cmask);
    float v = (float)X[i] * scale[c] + shift[c];
    if (do_relu) v = fmaxf(v, 0.f);
    if (residual) v += (float)residual[i];
    if (Yf) Yf[i] = v;
    if (Yh) Yh[i] = (_Float16)v;
  }
}

extern "C" void kernel_launch(void* const* d_in, const int* in_sizes, int n_in,
                              void* d_out, int out_size, void* d_ws, size_t ws_size,
                              hipStream_t stream)
{
  (void)in_sizes; (void)n_in; (void)out_size; (void)ws_size;
  const float* X     = (const float*)d_in[0];
  const float* adj   = (const float*)d_in[1];
  const float* adjg  = (const float*)d_in[2];
  const float* Wp    = (const float*)d_in[3];
  const float* gp    = (const float*)d_in[5];
  const float* betap = (const float*)d_in[6];

  float* out_h     = (float*)d_out;                       // [6144,256]
  float* out_embed = out_h + (size_t)NROW * DOUT;         // [6144,512]

  char* base = (char*)d_ws;
  size_t off = 0;
  auto alloc = [&](size_t bytes) -> void* {
    void* p = base + off;
    off += (bytes + 255) & ~(size_t)255;
    return p;
  };

  const long MN512 = (long)NROW * 512;

  _Float16* Ag  = (_Float16*)alloc((size_t)NROW * NROW * 2);   // adjg f16; reused as scores Sf
  _Float16* Sf  = Ag;
  uint32_t* bits = (uint32_t*)alloc((size_t)NROW * 192 * 4);
  _Float16* Pk  = (_Float16*)alloc((size_t)8 * MN512 * 2);     // split-K partials (f16)
  _Float16* XsT = (_Float16*)alloc((size_t)HDIM * NROW * 2);
  _Float16* Yh16 = (_Float16*)alloc((size_t)NROW * HDIM * 2);
  _Float16* Wph = (_Float16*)alloc((size_t)HDIM * HDIM * 2);
  _Float16* QKVW[3];
  for (int i = 0; i < 3; ++i) QKVW[i] = (_Float16*)alloc((size_t)1536 * HDIM * 2);
  _Float16* Woh[3];
  Woh[0] = (_Float16*)alloc((size_t)512 * 512 * 2);
  Woh[1] = (_Float16*)alloc((size_t)512 * 512 * 2);
  Woh[2] = (_Float16*)alloc((size_t)256 * 512 * 2);
  _Float16* QKVh = (_Float16*)alloc((size_t)NROW * 1536 * 2);
  _Float16* VTh  = (_Float16*)alloc((size_t)HDIM * NROW * 2);
  _Float16* AVh  = (_Float16*)alloc((size_t)NROW * HDIM * 2);
  _Float16* xh   = (_Float16*)alloc((size_t)NROW * HDIM * 2);  // pre-BN buffer (f16)
  _Float16* hb16A = (_Float16*)alloc((size_t)NROW * HDIM * 2);
  _Float16* hb16B = (_Float16*)alloc((size_t)NROW * HDIM * 2);
  float* dis  = (float*)alloc((size_t)NROW * 4);
  float* linv = (float*)alloc((size_t)NROW * 4);
  float* psum = (float*)alloc((size_t)96 * 512 * 4);
  float* psq  = (float*)alloc((size_t)96 * 512 * 4);
  float* bnsc = (float*)alloc(512 * 4);
  float* bnsh = (float*)alloc(512 * 4);

  const float qk_scale = 0.21022410381342863f;  // 512^(-1/4); folded into both Wq and Wk

  degree_convert<<<NROW, 256, 0, stream>>>(adjg, Ag, dis);
  build_mask<<<NROW, 192, 0, stream>>>(adj, bits);
  transpose_scale_f16<<<dim3(8, 96), 256, 0, stream>>>(X, dis, XsT, NROW, HDIM);

  {
    WConv w;
    int seg = 0;
    w.src[seg] = Wp; w.dst[seg] = Wph; w.n4[seg] = 512 * 512 / 4; w.scale[seg] = 1.f; ++seg;
    for (int i = 0; i < 3; ++i) {
      int o = (i < 2) ? 512 : 256;
      w.src[seg] = (const float*)d_in[7 + i * 7 + 0]; w.dst[seg] = QKVW[i];
      w.n4[seg] = 512 * 512 / 4; w.scale[seg] = qk_scale; ++seg;
      w.src[seg] = (const float*)d_in[7 + i * 7 + 1]; w.dst[seg] = QKVW[i] + 512 * 512;
      w.n4[seg] = 512 * 512 / 4; w.scale[seg] = qk_scale; ++seg;
      w.src[seg] = (const float*)d_in[7 + i * 7 + 2]; w.dst[seg] = QKVW[i] + 2 * 512 * 512;
      w.n4[seg] = 512 * 512 / 4; w.scale[seg] = 1.f; ++seg;
      w.src[seg] = (const float*)d_in[7 + i * 7 + 3]; w.dst[seg] = Woh[i];
      w.n4[seg] = o * 512 / 4; w.scale[seg] = 1.f; ++seg;
    }
    convert_weights<<<13 * 16, 256, 0, stream>>>(w);
  }

  // ---- embedding: h = BN( rowscale(dis) * (Ag @ XsT^T) @ Wp^T )   (bias cancels in BN)
  gemm256<<<dim3(24, 2, 8), 512, 0, stream>>>(Ag, NROW, XsT, NROW, Pk, 512, 768, MN512);
  reduce_splitk<<<1536, 256, 0, stream>>>(Pk, MN512, 8, 9, dis, nullptr, Yh16);
  gemm_f16<<<dim3(48, 4), 256, 0, stream>>>(Yh16, HDIM, Wph, HDIM, nullptr, xh, HDIM,
                                            512, nullptr, 0);
  bn_partial<<<96, 256, 0, stream>>>(xh, 512, psum, psq);
  bn_finalize<<<2, 256, 0, stream>>>(psum, psq, 512, gp, betap, bnsc, bnsh);
  bn_apply<<<2048, 256, 0, stream>>>(xh, bnsc, bnsh, nullptr, out_embed, hb16A,
                                     511, MN512, 0);

  _Float16* hbuf[2] = {hb16A, hb16B};
  int cur = 0;
  for (int i = 0; i < 3; ++i) {
    int o = (i < 2) ? 512 : 256;
    const float* gl = (const float*)d_in[7 + i * 7 + 5];
    const float* bl = (const float*)d_in[7 + i * 7 + 6];
    _Float16* hin = hbuf[cur];

    // fused QKV projection: [6144,1536]
    gemm_f16<<<dim3(48, 12), 256, 0, stream>>>(hin, HDIM, QKVW[i], HDIM, nullptr, QKVh, 1536,
                                               512, nullptr, 0);
    transpose_f16<<<dim3(8, 96), 256, 0, stream>>>(QKVh + 1024, 1536, VTh, NROW, HDIM);
    // raw scores (f16), then in-place masked softmax (unnormalized exp + linv)
    gemm256<<<dim3(24, 24), 512, 0, stream>>>(QKVh, 1536, QKVh + 512, 1536, Sf, NROW, 512, 0);
    softmax_mask16<<<NROW, 256, 0, stream>>>(Sf, bits, linv);
    // attn @ V (split-K 8), normalization via rowscale=linv in reduce
    gemm256<<<dim3(24, 2, 8), 512, 0, stream>>>(Sf, NROW, VTh, NROW, Pk, 512, 768, MN512);
    reduce_splitk<<<1536, 256, 0, stream>>>(Pk, MN512, 8, 9, linv, nullptr, AVh);
    // @ Wo^T (split-K 4; bias cancels in BN)
    long MNo = (long)NROW * o;
    gemm_f16<<<dim3(48, o / 128, 4), 256, 0, stream>>>(AVh, HDIM, Woh[i], HDIM,
                                                       nullptr, nullptr, o, 128, Pk, MNo);
    reduce_splitk<<<1536, 256, 0, stream>>>(Pk, MNo, 4, (o == 512) ? 9 : 8, nullptr,
                                            nullptr, xh);
    bn_partial<<<96, 256, 0, stream>>>(xh, o, psum, psq);
    bn_finalize<<<2, 256, 0, stream>>>(psum, psq, o, gl, bl, bnsc, bnsh);
    if (i < 2) {
      bn_apply<<<2048, 256, 0, stream>>>(xh, bnsc, bnsh, hin, nullptr, hbuf[cur ^ 1],
                                         o - 1, (long)NROW * o, 1);
      cur ^= 1;
    } else {
      bn_apply<<<2048, 256, 0, stream>>>(xh, bnsc, bnsh, nullptr, out_h, nullptr,
                                         o - 1, (long)NROW * o, 1);
    }
  }
}